// Round 14
// baseline (1659.154 us; speedup 1.0000x reference)
//
#include <hip/hip_runtime.h>
#include <math.h>

#define NN 50000
#define NE 120000
#define FN 64
#define NEA 16
#define NR 4
#define NH 4
#define HID 128
#define NL 3
#define IDE 32
#define RED 8
#define NG 64
#define NC 10
#define KH 128
#define FFH 256
#define NBIN (NR * NN)
#define SCAN_BLK ((NBIN + 1023) / 1024)

typedef short bf16x8 __attribute__((ext_vector_type(8)));
typedef float f32x4 __attribute__((ext_vector_type(4)));

__device__ __forceinline__ unsigned short f2b(float f) {
  unsigned u = __float_as_uint(f);
  unsigned r = (u + 0x7FFFu + ((u >> 16) & 1u)) >> 16;
  return (unsigned short)r;
}
__device__ __forceinline__ float b2f(unsigned short b) {
  return __uint_as_float((unsigned)b << 16);
}

__global__ void cvt_bf16(const float* __restrict__ s, unsigned short* __restrict__ d, int n4) {
  int i = blockIdx.x * blockDim.x + threadIdx.x;
  if (i >= n4) return;
  float4 v = ((const float4*)s)[i];
  ushort4 o;
  o.x = f2b(v.x); o.y = f2b(v.y); o.z = f2b(v.z); o.w = f2b(v.w);
  ((ushort4*)d)[i] = o;
}

// ---- GEMM core: 128x128 tile, optional A-row gather, LDS-staged bf16 epilogue ----
// pad 36 shorts (72B = 18 banks, gcd(18,32)=2): ds_read_b128 2-way only (free)
__device__ __forceinline__ void gemm_core(
    char* smem, const unsigned short* __restrict__ A, const int* __restrict__ rowlist,
    const unsigned short* __restrict__ W,
    const float* __restrict__ bias, float* __restrict__ Cf, unsigned short* __restrict__ Cb,
    int nrows, int K, int mout, int act, int rowBase, int colBase) {
  unsigned short (*As)[36] = (unsigned short (*)[36])smem;
  unsigned short (*Ws)[36] = (unsigned short (*)[36])(smem + 9216);
  int t = threadIdx.x;
  int lane = t & 63, w = t >> 6;
  int wm = w >> 1, wn = w & 1;
  int q = lane >> 4, mr = lane & 15;
  f32x4 acc[4][4] = {};
  for (int k0 = 0; k0 < K; k0 += 32) {
#pragma unroll
    for (int half = 0; half < 2; ++half) {
      int c = t + half * 256;
      int row = c >> 2, c16 = c & 3;
      int gr = rowBase + row;
      bf16x8 av = {0, 0, 0, 0, 0, 0, 0, 0};
      if (gr < nrows) {
        int ar = rowlist ? rowlist[gr] : gr;
        av = *(const bf16x8*)(A + (size_t)ar * K + k0 + c16 * 8);
      }
      *(bf16x8*)&As[row][c16 * 8] = av;
      bf16x8 wv = *(const bf16x8*)(W + (size_t)(colBase + row) * K + k0 + c16 * 8);
      *(bf16x8*)&Ws[row][c16 * 8] = wv;
    }
    __syncthreads();
    bf16x8 af[4], bfr[4];
#pragma unroll
    for (int mt = 0; mt < 4; ++mt) af[mt] = *(const bf16x8*)&As[wm * 64 + mt * 16 + mr][q * 8];
#pragma unroll
    for (int nt = 0; nt < 4; ++nt) bfr[nt] = *(const bf16x8*)&Ws[wn * 64 + nt * 16 + mr][q * 8];
#pragma unroll
    for (int mt = 0; mt < 4; ++mt)
#pragma unroll
      for (int nt = 0; nt < 4; ++nt)
        acc[mt][nt] = __builtin_amdgcn_mfma_f32_16x16x32_bf16(af[mt], bfr[nt], acc[mt][nt], 0, 0, 0);
    __syncthreads();
  }
  if (Cb) {
    unsigned short (*Es)[136] = (unsigned short (*)[136])smem;
#pragma unroll
    for (int ph = 0; ph < 2; ++ph) {
      if (wm == ph) {
#pragma unroll
        for (int mt = 0; mt < 4; ++mt)
#pragma unroll
          for (int nt = 0; nt < 4; ++nt)
#pragma unroll
            for (int r = 0; r < 4; ++r) {
              float v = acc[mt][nt][r] + bias[colBase + wn * 64 + nt * 16 + mr];
              if (act) v = v / (1.f + expf(-v));
              Es[mt * 16 + q * 4 + r][wn * 64 + nt * 16 + mr] = f2b(v);
            }
      }
      __syncthreads();
      int rl = t >> 2, co = (t & 3) * 32;
      int grow = rowBase + ph * 64 + rl;
      if (grow < nrows) {
        unsigned short* dst = Cb + (size_t)grow * mout + colBase + co;
#pragma unroll
        for (int j = 0; j < 4; ++j)
          *(bf16x8*)(dst + j * 8) = *(const bf16x8*)&Es[rl][co + j * 8];
      }
      __syncthreads();
    }
  } else {
#pragma unroll
    for (int mt = 0; mt < 4; ++mt)
#pragma unroll
      for (int nt = 0; nt < 4; ++nt)
#pragma unroll
        for (int r = 0; r < 4; ++r) {
          int row = rowBase + wm * 64 + mt * 16 + q * 4 + r;
          int col = colBase + wn * 64 + nt * 16 + mr;
          if (row < nrows) {
            float v = acc[mt][nt][r] + bias[col];
            if (act) v = v / (1.f + expf(-v));
            Cf[(size_t)row * mout + col] = v;
          }
        }
  }
}

// XCD-aware full GEMM (dispatch is round-robin over 8 XCDs: bid&7 = XCD)
__global__ __launch_bounds__(256) void gemm_bf16(
    const unsigned short* __restrict__ A, const unsigned short* __restrict__ W,
    const float* __restrict__ bias, float* __restrict__ Cf, unsigned short* __restrict__ Cb,
    int nrows, int K, int mout, int act, int ncol) {
  __shared__ char smem[20480];
  int nbr = (nrows + 127) >> 7;
  int rpx = (nbr + 7) >> 3;
  int xcd = blockIdx.x & 7, j = blockIdx.x >> 3;
  int rowT = xcd * rpx + j / ncol;
  int cy = j - (j / ncol) * ncol;
  if (rowT >= nbr) return;
  gemm_core(smem, A, nullptr, W, bias, Cf, Cb, nrows, K, mout, act, rowT * 128, cy * 128);
}

// row-gather GEMM over device-side row count (xl for src nodes / xr for hot dsts)
__global__ __launch_bounds__(256) void gemm_rows(
    const unsigned short* __restrict__ A, const int* __restrict__ rowlist,
    const int* __restrict__ nrowsp, const unsigned short* __restrict__ W,
    const float* __restrict__ bias, unsigned short* __restrict__ Cb,
    int K, int mout, int ncol) {
  __shared__ char smem[20480];
  int nrows = *nrowsp;
  int bid = blockIdx.x;
  int rowT = bid / ncol, cy = bid - rowT * ncol;
  if (rowT * 128 >= nrows) return;
  gemm_core(smem, A, rowlist, W, bias, nullptr, Cb, nrows, K, mout, 0, rowT * 128, cy * 128);
}

__global__ void build_xin_bf(const float* __restrict__ x, const int* __restrict__ idtok,
                             const float* __restrict__ emb, unsigned short* __restrict__ xin) {
  int i = blockIdx.x * blockDim.x + threadIdx.x;
  if (i >= NN * 96) return;
  int n = i / 96, k = i - n * 96;
  float v = (k < FN) ? x[(size_t)n * FN + k] : emb[(size_t)idtok[n] * IDE + (k - FN)];
  xin[i] = f2b(v);
}

// ---- CSR by (rel, dst) ----
__global__ void hist_bin(const int* __restrict__ ei, const int* __restrict__ et,
                         int* __restrict__ bcnt) {
  int e = blockIdx.x * blockDim.x + threadIdx.x;
  if (e >= NE) return;
  atomicAdd(&bcnt[et[e] * NN + ei[NE + e]], 1);
}
__global__ __launch_bounds__(256) void scan1(const int* __restrict__ cnt,
                                             int* __restrict__ csroff, int* __restrict__ bsum) {
  __shared__ int lds[256];
  int b = blockIdx.x, t = threadIdx.x;
  int base = b * 1024 + t * 4;
  int v[4];
#pragma unroll
  for (int j = 0; j < 4; ++j) v[j] = (base + j < NBIN) ? cnt[base + j] : 0;
  int tot = v[0] + v[1] + v[2] + v[3];
  lds[t] = tot;
  __syncthreads();
  for (int off = 1; off < 256; off <<= 1) {
    int x = (t >= off) ? lds[t - off] : 0;
    __syncthreads();
    lds[t] += x;
    __syncthreads();
  }
  if (t == 255) bsum[b] = lds[255];
  int run = lds[t] - tot;
#pragma unroll
  for (int j = 0; j < 4; ++j) {
    if (base + j < NBIN) csroff[base + j] = run;
    run += v[j];
  }
}
__global__ __launch_bounds__(256) void scan2(int* __restrict__ bsum) {
  __shared__ int lds[256];
  int t = threadIdx.x;
  int v = (t < SCAN_BLK) ? bsum[t] : 0;
  lds[t] = v;
  __syncthreads();
  for (int off = 1; off < 256; off <<= 1) {
    int x = (t >= off) ? lds[t - off] : 0;
    __syncthreads();
    lds[t] += x;
    __syncthreads();
  }
  if (t < SCAN_BLK) bsum[t] = lds[t] - v;
}
__global__ void scan3(int* __restrict__ csroff, const int* __restrict__ bsum) {
  int i = blockIdx.x * blockDim.x + threadIdx.x;
  if (i < NBIN) csroff[i] += bsum[i >> 10];
  if (i == 0) csroff[NBIN] = NE;
}
__global__ void scatter_bin(const int* __restrict__ ei, const int* __restrict__ et,
                            const int* __restrict__ csroff, int* __restrict__ cur,
                            int* __restrict__ elist) {
  int e = blockIdx.x * blockDim.x + threadIdx.x;
  if (e >= NE) return;
  int bin = et[e] * NN + ei[NE + e];
  int p = atomicAdd(&cur[bin], 1);
  elist[csroff[bin] + p] = e;
}
// DETERMINISM: atomic scatter order varies call-to-call; sort each bin.
__global__ void sort_bins(const int* __restrict__ csroff, int* __restrict__ elist) {
  int b = blockIdx.x * blockDim.x + threadIdx.x;
  if (b >= NBIN) return;
  int s = csroff[b], e = csroff[b + 1];
  for (int i = s + 1; i < e; ++i) {
    int key = elist[i];
    int j = i - 1;
    while (j >= s && elist[j] > key) { elist[j + 1] = elist[j]; --j; }
    elist[j + 1] = key;
  }
}
__global__ void gather_edge(const int* __restrict__ ei, const int* __restrict__ elist,
                            const float* __restrict__ eattr,
                            int* __restrict__ rsrc, float* __restrict__ eacsr) {
  int p = blockIdx.x * blockDim.x + threadIdx.x;
  if (p >= NE) return;
  int e = elist[p];
  rsrc[p] = ei[e];
  const float4* s = (const float4*)(eattr + (size_t)e * NEA);
  float4* d = (float4*)(eacsr + (size_t)p * NEA);
#pragma unroll
  for (int j = 0; j < 4; ++j) d[j] = s[j];
}
// mark nodes that are a src of >=1 edge per rel (benign-race flag writes)
__global__ void mark_src(const int* __restrict__ ei, const int* __restrict__ et,
                         int* __restrict__ srcflag) {
  int e = blockIdx.x * blockDim.x + threadIdx.x;
  if (e >= NE) return;
  srcflag[et[e] * NN + ei[e]] = 1;
}
// compact src flags -> srclist + srcmap (block-hierarchical, padded counters)
__global__ __launch_bounds__(256) void build_src(
    const int* __restrict__ srcflag, int* __restrict__ nsrc,
    int* __restrict__ srclist, int* __restrict__ srcmap) {
  __shared__ int wc[4][4];
  __shared__ int base4[4];
  int t = threadIdx.x, wave = t >> 6, lane = t & 63;
  int b = blockIdx.x * 256 + t;
  bool valid = b < NBIN;
  int rel = valid ? b / NN : 0;
  bool f = valid && srcflag[b];
#pragma unroll
  for (int rr = 0; rr < 4; ++rr) {
    unsigned long long m = __ballot(f && rel == rr);
    if (lane == 0) wc[wave][rr] = __popcll(m);
  }
  __syncthreads();
  if (t < 4) {
    int sum = wc[0][t] + wc[1][t] + wc[2][t] + wc[3][t];
    base4[t] = sum ? atomicAdd(&nsrc[t * 16], sum) : 0;
  }
  __syncthreads();
#pragma unroll
  for (int rr = 0; rr < 4; ++rr) {
    unsigned long long m = __ballot(f && rel == rr);
    if (f && rel == rr) {
      int before = 0;
#pragma unroll
      for (int wv = 0; wv < 4; ++wv) if (wv < wave) before += wc[wv][rr];
      int pos = base4[rr] + before + __popcll(m & ((1ull << lane) - 1ull));
      srclist[rr * NN + pos] = b - rr * NN;
      srcmap[b] = pos;
    }
  }
}
// remap CSR src ids -> dense xl row indices
__global__ void remap_rsrc(const int* __restrict__ csroff, const int* __restrict__ rsrc,
                           const int* __restrict__ srcmap, int* __restrict__ rsrcx) {
  int p = blockIdx.x * blockDim.x + threadIdx.x;
  if (p >= NE) return;
  int rel = (p >= csroff[NN]) + (p >= csroff[2 * NN]) + (p >= csroff[3 * NN]);
  rsrcx[p] = srcmap[rel * NN + rsrc[p]];
}
// per-rel solo (deg==1: mapped src + dst) + hot (deg>=2) lists.
__global__ __launch_bounds__(256) void build_hot(
    const int* __restrict__ csroff, const int* __restrict__ rsrc,
    const int* __restrict__ srcmap,
    int* __restrict__ nsolo, int* __restrict__ nhot,
    int* __restrict__ solosrc, int* __restrict__ solodst, int* __restrict__ hotlist) {
  __shared__ int wsc[4][4], whc[4][4];
  __shared__ int sbase[4], hbase[4];
  int t = threadIdx.x, wave = t >> 6, lane = t & 63;
  int b = blockIdx.x * 256 + t;
  bool valid = b < NBIN;
  int cnt = 0, rel = 0, s = 0;
  if (valid) { s = csroff[b]; cnt = csroff[b + 1] - s; rel = b / NN; }
  bool solo = valid && cnt == 1;
  bool hot = valid && cnt >= 2;
#pragma unroll
  for (int rr = 0; rr < 4; ++rr) {
    unsigned long long ms = __ballot(solo && rel == rr);
    unsigned long long mh = __ballot(hot && rel == rr);
    if (lane == 0) { wsc[wave][rr] = __popcll(ms); whc[wave][rr] = __popcll(mh); }
  }
  __syncthreads();
  if (t < 4) {
    int ssum = wsc[0][t] + wsc[1][t] + wsc[2][t] + wsc[3][t];
    int hsum = whc[0][t] + whc[1][t] + whc[2][t] + whc[3][t];
    sbase[t] = ssum ? atomicAdd(&nsolo[t * 16], ssum) : 0;
    hbase[t] = hsum ? atomicAdd(&nhot[t * 16], hsum) : 0;
  }
  __syncthreads();
#pragma unroll
  for (int rr = 0; rr < 4; ++rr) {
    unsigned long long ms = __ballot(solo && rel == rr);
    if (solo && rel == rr) {
      int before = 0;
#pragma unroll
      for (int wv = 0; wv < 4; ++wv) if (wv < wave) before += wsc[wv][rr];
      int pos = sbase[rr] + before + __popcll(ms & ((1ull << lane) - 1ull));
      solosrc[rr * NN + pos] = srcmap[rr * NN + rsrc[s]];  // mapped xl row
      solodst[rr * NN + pos] = b - rr * NN;
    }
    unsigned long long mh = __ballot(hot && rel == rr);
    if (hot && rel == rr) {
      int before = 0;
#pragma unroll
      for (int wv = 0; wv < 4; ++wv) if (wv < wave) before += whc[wv][rr];
      int pos = hbase[rr] + before + __popcll(mh & ((1ull << lane) - 1ull));
      hotlist[rr * NN + pos] = b - rr * NN;
    }
  }
}

__global__ void gate_cb(const float* __restrict__ rg, const float* __restrict__ cbias,
                        float* __restrict__ gate, float* __restrict__ cb) {
  __shared__ float g[NR];
  int t = threadIdx.x;
  if (t == 0) {
    float mx = rg[0];
    for (int r = 1; r < NR; ++r) mx = fmaxf(mx, rg[r]);
    float s = 0.f, tmp[NR];
    for (int r = 0; r < NR; ++r) { tmp[r] = expf(rg[r] - mx); s += tmp[r]; }
    for (int r = 0; r < NR; ++r) { g[r] = tmp[r] / s; gate[r] = g[r]; }
  }
  __syncthreads();
  float c = 0.f;
  for (int r = 0; r < NR; ++r) c += g[r] * cbias[r * HID + t];
  cb[t] = c;
}

// ---- deg==1 dsts: weight == 1 exactly. One WAVE per dst, no sync. ----
__global__ __launch_bounds__(256) void edge_solo(
    const int* __restrict__ solosrc, const int* __restrict__ solodst,
    const int* __restrict__ nsolo, const unsigned short* __restrict__ xlb,
    float* __restrict__ hmsg, const float* __restrict__ gate,
    int rel, int HP, int stride) {
  int wave = threadIdx.x >> 6, lane = threadIdx.x & 63;
  float g4 = gate[rel] * 0.25f;
  int nw = nsolo[rel * 16];
  for (int i = blockIdx.x * 4 + wave; i < nw; i += gridDim.x * 4) {
    int src = solosrc[rel * NN + i];  // mapped xl row
    int dst = solodst[rel * NN + i];
    const unsigned short* xp = xlb + (size_t)src * stride;
    float v0 = 0.f, v1 = 0.f;
    for (int h = 0; h < HP; ++h) {
      v0 += b2f(xp[h * 128 + lane]);
      v1 += b2f(xp[h * 128 + 64 + lane]);
    }
    hmsg[(size_t)dst * HID + lane] += g4 * v0;
    hmsg[(size_t)dst * HID + 64 + lane] += g4 * v1;
  }
}

// ---- deg>=2 dsts: block per dst, online softmax over SORTED csr order. ----
__global__ __launch_bounds__(256) void edge_hot(
    const int* __restrict__ csroff, const int* __restrict__ rsrcx,
    const float* __restrict__ eacsr, const float* __restrict__ relembp,
    const float* __restrict__ wedgep, const float* __restrict__ attwp,
    const unsigned short* __restrict__ xlb, const unsigned short* __restrict__ xrh,
    const int* __restrict__ hotlist, const int* __restrict__ nhot,
    float* __restrict__ hmsg, const float* __restrict__ gate,
    int rel, int HP, int stride) {
  __shared__ float lds[4][128];
  int wave = threadIdx.x >> 6, lane = threadIdx.x & 63;
  bool act = wave < HP;
  int hh = act ? wave : 0;
  float wreg[2][24], areg[2];
#pragma unroll
  for (int j = 0; j < 2; ++j) {
    int col = hh * 128 + j * 64 + lane;
    const float* wp = wedgep + (size_t)col * 24;
#pragma unroll
    for (int k = 0; k < 24; ++k) wreg[j][k] = wp[k];
    areg[j] = attwp[col];
  }
  float evr0 = 0.f, evr1 = 0.f;
#pragma unroll
  for (int k = 0; k < 8; ++k) {
    float rk = relembp[k];
    evr0 += rk * wreg[0][NEA + k];
    evr1 += rk * wreg[1][NEA + k];
  }
  float g4 = gate[rel] * 0.25f;
  int nh = nhot[rel * 16];
  for (int wi = blockIdx.x; wi < nh; wi += gridDim.x) {
    int dst = hotlist[rel * NN + wi];
    int s = csroff[rel * NN + dst], e = csroff[rel * NN + dst + 1];
    if (act) {
      const unsigned short* xrp = xrh + (size_t)wi * stride;
      float xr0 = b2f(xrp[hh * 128 + lane]);
      float xr1 = b2f(xrp[hh * 128 + 64 + lane]);
      float m = -3.4e38f, den = 0.f, acc0 = 0.f, acc1 = 0.f;
      for (int p = s; p < e; ++p) {
        int src = rsrcx[p];  // mapped xl row
        const float* eap = eacsr + (size_t)p * NEA;
        float er[NEA];
#pragma unroll
        for (int k = 0; k < NEA; ++k) er[k] = eap[k];
        float eev0 = evr0, eev1 = evr1;
#pragma unroll
        for (int k = 0; k < NEA; ++k) { eev0 += er[k] * wreg[0][k]; eev1 += er[k] * wreg[1][k]; }
        float xl0 = b2f(xlb[(size_t)src * stride + hh * 128 + lane]);
        float xl1 = b2f(xlb[(size_t)src * stride + hh * 128 + 64 + lane]);
        float s0 = xl0 + xr0 + eev0; s0 = (s0 > 0.f) ? s0 : 0.2f * s0;
        float s1 = xl1 + xr1 + eev1; s1 = (s1 > 0.f) ? s1 : 0.2f * s1;
        float lg = s0 * areg[0] + s1 * areg[1];
#pragma unroll
        for (int o = 32; o > 0; o >>= 1) lg += __shfl_xor(lg, o, 64);
        float mn = fmaxf(m, lg);
        float sc = expf(m - mn);
        float ex = expf(lg - mn);
        den = den * sc + ex;
        acc0 = acc0 * sc + ex * xl0;
        acc1 = acc1 * sc + ex * xl1;
        m = mn;
      }
      float w = g4 / den;
      lds[wave][lane] = acc0 * w;
      lds[wave][64 + lane] = acc1 * w;
    }
    __syncthreads();
    if (wave < 2) {
      int d = wave * 64 + lane;
      float v = 0.f;
      for (int h = 0; h < HP; ++h) v += lds[h][d];
      hmsg[(size_t)dst * HID + d] += v;
    }
    __syncthreads();
  }
}

// ---- h = layernorm(h + add (+ cb)); also emits bf16 copy ----
__global__ __launch_bounds__(256) void add_ln(
    float* __restrict__ h, const float* __restrict__ add, const float* __restrict__ cb,
    const float* __restrict__ w, const float* __restrict__ b,
    unsigned short* __restrict__ hbf, int nrows) {
  int wave = threadIdx.x >> 6, lane = threadIdx.x & 63;
  int row = blockIdx.x * 4 + wave;
  if (row >= nrows) return;
  size_t base = (size_t)row * HID;
  float x0 = h[base + lane] + add[base + lane];
  float x1 = h[base + 64 + lane] + add[base + 64 + lane];
  if (cb) { x0 += cb[lane]; x1 += cb[64 + lane]; }
  float s = x0 + x1;
#pragma unroll
  for (int o = 32; o > 0; o >>= 1) s += __shfl_xor(s, o, 64);
  float mean = s * (1.f / 128.f);
  float d0 = x0 - mean, d1 = x1 - mean;
  float v = d0 * d0 + d1 * d1;
#pragma unroll
  for (int o = 32; o > 0; o >>= 1) v += __shfl_xor(v, o, 64);
  float inv = 1.f / sqrtf(v * (1.f / 128.f) + 1e-5f);
  float y0 = d0 * inv * w[lane] + b[lane];
  float y1 = d1 * inv * w[64 + lane] + b[64 + lane];
  h[base + lane] = y0;
  h[base + 64 + lane] = y1;
  hbf[base + lane] = f2b(y0);
  hbf[base + 64 + lane] = f2b(y1);
}

// ---- readout: deterministic (binary-search bounds, fixed partial slots) ----
__global__ void group_bounds(const int* __restrict__ batch, int* __restrict__ gstart) {
  int g = threadIdx.x + blockIdx.x * blockDim.x;
  if (g > NG) return;
  int lo = 0, hi = NN;
  while (lo < hi) {
    int mid = (lo + hi) >> 1;
    if (batch[mid] < g) lo = mid + 1; else hi = mid;
  }
  gstart[g] = lo;
}
__global__ __launch_bounds__(128) void readout_part2(
    const float* __restrict__ h, const int* __restrict__ gstart,
    float* __restrict__ psum, float* __restrict__ pmax) {
  int g = blockIdx.x, s = blockIdx.y, t = threadIdx.x;
  int r0 = gstart[g], r1 = gstart[g + 1];
  float acc = 0.f, mx = -3.4e38f;
  for (int row = r0 + s; row < r1; row += 8) {
    float v = h[(size_t)row * HID + t];
    acc += v;
    mx = fmaxf(mx, v);
  }
  psum[((size_t)g * 8 + s) * HID + t] = acc;
  pmax[((size_t)g * 8 + s) * HID + t] = mx;
}
__global__ __launch_bounds__(256) void readout_final(
    const int* __restrict__ gstart, const float* __restrict__ psum,
    const float* __restrict__ pmax, const float* __restrict__ w,
    const float* __restrict__ b, float* __restrict__ g) {
  int bg = blockIdx.x, t = threadIdx.x;
  __shared__ float red[256];
  float c = fmaxf((float)(gstart[bg + 1] - gstart[bg]), 1.f);
  float x;
  if (t < HID) {
    float ssum = 0.f;
    for (int s = 0; s < 8; ++s) ssum += psum[((size_t)bg * 8 + s) * HID + t];
    x = ssum / c;
  } else {
    float mx = -3.4e38f;
    for (int s = 0; s < 8; ++s) mx = fmaxf(mx, pmax[((size_t)bg * 8 + s) * HID + (t - HID)]);
    x = mx;
  }
  red[t] = x;
  __syncthreads();
  for (int s = 128; s > 0; s >>= 1) {
    if (t < s) red[t] += red[t + s];
    __syncthreads();
  }
  float mean = red[0] * (1.f / 256.f);
  __syncthreads();
  float d = x - mean;
  red[t] = d * d;
  __syncthreads();
  for (int s = 128; s > 0; s >>= 1) {
    if (t < s) red[t] += red[t + s];
    __syncthreads();
  }
  float inv = 1.f / sqrtf(red[0] * (1.f / 256.f) + 1e-5f);
  g[(size_t)bg * 256 + t] = d * inv * w[t] + b[t];
}

__device__ __forceinline__ void bspline8(float x, const float* __restrict__ t,
                                         float* __restrict__ out) {
  float bs[11];
#pragma unroll
  for (int j = 0; j < 11; ++j) bs[j] = (x >= t[j] && x < t[j + 1]) ? 1.f : 0.f;
#pragma unroll
  for (int k = 1; k <= 3; ++k) {
    for (int j = 0; j < 11 - k; ++j) {
      bs[j] = (x - t[j]) / (t[j + k] - t[j]) * bs[j] +
              (t[j + k + 1] - x) / (t[j + k + 1] - t[j + 1]) * bs[j + 1];
    }
  }
#pragma unroll
  for (int j = 0; j < 8; ++j) out[j] = bs[j];
}

// ---- KAN1, K-chunked into fixed partial slots (deterministic) ----
__global__ __launch_bounds__(128) void kan1_part(
    const float* __restrict__ g, const float* __restrict__ bw,
    const float* __restrict__ sw, const float* __restrict__ sc,
    const float* __restrict__ grid, float* __restrict__ zpart) {
  int bg = blockIdx.x, ch = blockIdx.y, t = threadIdx.x;
  int base = ch * 32;
  __shared__ float B[32][8];
  __shared__ float sg[32];
  if (t < 32) {
    float x = g[(size_t)bg * 256 + base + t];
    sg[t] = x / (1.f + expf(-x));
    bspline8(x, grid + (size_t)(base + t) * 12, B[t]);
  }
  __syncthreads();
  float acc = 0.f;
  for (int i = 0; i < 32; ++i) {
    int col = base + i;
    acc += sg[i] * bw[(size_t)t * 256 + col];
    const float* swp = sw + ((size_t)t * 256 + col) * 8;
    float sp = 0.f;
#pragma unroll
    for (int k = 0; k < 8; ++k) sp += B[i][k] * swp[k];
    acc += sp * sc[(size_t)t * 256 + col];
  }
  zpart[((size_t)ch * NG + bg) * KH + t] = acc;
}

__global__ __launch_bounds__(128) void kan2(
    const float* __restrict__ zpart, const float* __restrict__ bw,
    const float* __restrict__ sw, const float* __restrict__ sc,
    const float* __restrict__ grid, float* __restrict__ out) {
  int bg = blockIdx.x, t = threadIdx.x;
  __shared__ float B[128][8];
  __shared__ float sz[128];
  float x = 0.f;
  for (int ch = 0; ch < 8; ++ch) x += zpart[((size_t)ch * NG + bg) * KH + t];
  sz[t] = x / (1.f + expf(-x));
  bspline8(x, grid + (size_t)t * 12, B[t]);
  __syncthreads();
  if (t < NC) {
    float acc = 0.f;
    for (int i = 0; i < 128; ++i) {
      acc += sz[i] * bw[(size_t)t * 128 + i];
      const float* swp = sw + ((size_t)t * 128 + i) * 8;
      float sp = 0.f;
#pragma unroll
      for (int k = 0; k < 8; ++k) sp += B[i][k] * swp[k];
      acc += sp * sc[(size_t)t * 128 + i];
    }
    out[(size_t)bg * NC + t] = acc;
  }
}

extern "C" void kernel_launch(void* const* d_in, const int* in_sizes, int n_in,
                              void* d_out, int out_size, void* d_ws, size_t ws_size,
                              hipStream_t stream) {
  const float* x       = (const float*)d_in[0];
  const float* eattr   = (const float*)d_in[1];
  const int*   idtok   = (const int*)d_in[2];
  const int*   ei      = (const int*)d_in[3];
  const int*   etype   = (const int*)d_in[4];
  const int*   batch   = (const int*)d_in[5];
  const float* idemb   = (const float*)d_in[6];
  const float* inw     = (const float*)d_in[7];
  const float* inb     = (const float*)d_in[8];
  const float* relemb  = (const float*)d_in[9];
  const float* linlw   = (const float*)d_in[10];
  const float* linlb   = (const float*)d_in[11];
  const float* linrw   = (const float*)d_in[12];
  const float* linrb   = (const float*)d_in[13];
  const float* linew   = (const float*)d_in[14];
  const float* attw    = (const float*)d_in[15];
  const float* convb   = (const float*)d_in[16];
  const float* relgate = (const float*)d_in[17];
  const float* n1w     = (const float*)d_in[18];
  const float* n1b     = (const float*)d_in[19];
  const float* n2w     = (const float*)d_in[20];
  const float* n2b     = (const float*)d_in[21];
  const float* f1w     = (const float*)d_in[22];
  const float* f1bias  = (const float*)d_in[23];
  const float* f2w     = (const float*)d_in[24];
  const float* f2bias  = (const float*)d_in[25];
  const float* rnw     = (const float*)d_in[26];
  const float* rnb     = (const float*)d_in[27];
  const float* bw1     = (const float*)d_in[28];
  const float* sw1     = (const float*)d_in[29];
  const float* sc1     = (const float*)d_in[30];
  const float* grid1   = (const float*)d_in[31];
  const float* bw2     = (const float*)d_in[32];
  const float* sw2     = (const float*)d_in[33];
  const float* sc2     = (const float*)d_in[34];
  const float* grid2   = (const float*)d_in[35];
  float* out = (float*)d_out;
  (void)in_sizes; (void)n_in; (void)out_size;

  auto needed = [](int HP) -> size_t {
    auto al = [](size_t b) { return (b + 255) & ~(size_t)255; };
    size_t o = 0;
    o += al((size_t)NN * HID * 4) * 2;            // h, hmsg
    o += al((size_t)NN * HID * 2);                // hbf
    o += al((size_t)NN * 128 * HP * 2) * 2;       // xlb, xrh
    o += al((size_t)NE * 4) * 3;                  // elist, rsrc, rsrcx
    o += al((size_t)NE * NEA * 4);                // eacsr
    o += al((size_t)NBIN * 8 + 8);                // bcnt+cur
    o += al((size_t)(NBIN + 1) * 4);              // csroff
    o += al((size_t)SCAN_BLK * 4);                // bsum
    o += al((size_t)NR * NN * 4) * 4;             // hotlist, solosrc, solodst, srclist
    o += al((size_t)NBIN * 4) * 2;                // srcflag, srcmap
    o += al(1024);                                // padded counters
    o += al((size_t)NL * NR * 512 * 128 * 2) * 2; // linlwb, linrwb
    o += al((size_t)NL * 256 * 128 * 2) * 2;      // f1wb, f2wb
    o += al((size_t)128 * 96 * 2);                // inwb
    o += al(NR * 4) + al(HID * 4);
    o += al((size_t)(NG + 1) * 4);                // gstart
    o += al((size_t)NG * 8 * HID * 4) * 2;        // psum, pmax
    o += al((size_t)8 * NG * KH * 4);             // zpart
    o += al((size_t)NG * 256 * 4);                // g
    return o;
  };
  const int HP = (needed(4) <= ws_size) ? 4 : 2;
  const int passes = NH / HP;
  const int stride = HP * 128;

  char* p = (char*)d_ws;
  auto alloc = [&](size_t bytes) { void* q = (void*)p; p += (bytes + 255) & ~(size_t)255; return q; };
  float* h    = (float*)alloc((size_t)NN * HID * 4);
  float* hmsg = (float*)alloc((size_t)NN * HID * 4);
  unsigned short* hbf = (unsigned short*)alloc((size_t)NN * HID * 2);
  unsigned short* xlb = (unsigned short*)alloc((size_t)NN * 128 * HP * 2);
  unsigned short* xrh = (unsigned short*)alloc((size_t)NN * 128 * HP * 2);
  int* elist = (int*)alloc((size_t)NE * 4);
  int* rsrc  = (int*)alloc((size_t)NE * 4);
  int* rsrcx = (int*)alloc((size_t)NE * 4);
  float* eacsr = (float*)alloc((size_t)NE * NEA * 4);
  int* bcnt  = (int*)alloc((size_t)NBIN * 8 + 8);
  int* cur   = bcnt + NBIN;
  int* csroff = (int*)alloc((size_t)(NBIN + 1) * 4);
  int* bsum  = (int*)alloc((size_t)SCAN_BLK * 4);
  int* hotlist = (int*)alloc((size_t)NR * NN * 4);
  int* solosrc = (int*)alloc((size_t)NR * NN * 4);
  int* solodst = (int*)alloc((size_t)NR * NN * 4);
  int* srclist = (int*)alloc((size_t)NR * NN * 4);
  int* srcflag = (int*)alloc((size_t)NBIN * 4);
  int* srcmap  = (int*)alloc((size_t)NBIN * 4);
  int* cnts    = (int*)alloc(1024);  // nsolo[r*16], nhot[64+r*16], nsrc[128+r*16]
  int* nsolo   = cnts;
  int* nhot    = cnts + 64;
  int* nsrc    = cnts + 128;
  unsigned short* linlwb = (unsigned short*)alloc((size_t)NL * NR * 512 * 128 * 2);
  unsigned short* linrwb = (unsigned short*)alloc((size_t)NL * NR * 512 * 128 * 2);
  unsigned short* f1wb   = (unsigned short*)alloc((size_t)NL * 256 * 128 * 2);
  unsigned short* f2wb   = (unsigned short*)alloc((size_t)NL * 128 * 256 * 2);
  unsigned short* inwb   = (unsigned short*)alloc((size_t)128 * 96 * 2);
  float* gate = (float*)alloc(NR * 4);
  float* cb   = (float*)alloc(HID * 4);
  int* gstart = (int*)alloc((size_t)(NG + 1) * 4);
  float* psum = (float*)alloc((size_t)NG * 8 * HID * 4);
  float* pmax = (float*)alloc((size_t)NG * 8 * HID * 4);
  float* zpart = (float*)alloc((size_t)8 * NG * KH * 4);
  float* g = (float*)alloc((size_t)NG * 256 * 4);
  unsigned short* xinbf = xlb;
  unsigned short* f1buf = xlb;

  const int NB = (NN + 127) / 128;
  const int RPX = (NB + 7) / 8;

  {
    int n;
    n = NL * NR * 512 * 128 / 4;
    cvt_bf16<<<(n + 255) / 256, 256, 0, stream>>>(linlw, linlwb, n);
    cvt_bf16<<<(n + 255) / 256, 256, 0, stream>>>(linrw, linrwb, n);
    n = NL * 256 * 128 / 4;
    cvt_bf16<<<(n + 255) / 256, 256, 0, stream>>>(f1w, f1wb, n);
    cvt_bf16<<<(n + 255) / 256, 256, 0, stream>>>(f2w, f2wb, n);
    n = 128 * 96 / 4;
    cvt_bf16<<<(n + 255) / 256, 256, 0, stream>>>(inw, inwb, n);
  }

  hipMemsetAsync(bcnt, 0, (size_t)NBIN * 8 + 8, stream);
  hipMemsetAsync(srcflag, 0, (size_t)NBIN * 4, stream);
  hipMemsetAsync(cnts, 0, 1024, stream);
  hist_bin<<<(NE + 255) / 256, 256, 0, stream>>>(ei, etype, bcnt);
  scan1<<<SCAN_BLK, 256, 0, stream>>>(bcnt, csroff, bsum);
  scan2<<<1, 256, 0, stream>>>(bsum);
  scan3<<<(NBIN + 256) / 256, 256, 0, stream>>>(csroff, bsum);
  scatter_bin<<<(NE + 255) / 256, 256, 0, stream>>>(ei, etype, csroff, cur, elist);
  sort_bins<<<(NBIN + 255) / 256, 256, 0, stream>>>(csroff, elist);
  gather_edge<<<(NE + 255) / 256, 256, 0, stream>>>(ei, elist, eattr, rsrc, eacsr);
  mark_src<<<(NE + 255) / 256, 256, 0, stream>>>(ei, etype, srcflag);
  build_src<<<(NBIN + 255) / 256, 256, 0, stream>>>(srcflag, nsrc, srclist, srcmap);
  remap_rsrc<<<(NE + 255) / 256, 256, 0, stream>>>(csroff, rsrc, srcmap, rsrcx);
  build_hot<<<(NBIN + 255) / 256, 256, 0, stream>>>(csroff, rsrc, srcmap, nsolo, nhot,
                                                    solosrc, solodst, hotlist);

  build_xin_bf<<<(NN * 96 + 255) / 256, 256, 0, stream>>>(x, idtok, idemb, xinbf);
  gemm_bf16<<<8 * RPX, 256, 0, stream>>>(xinbf, inwb, inb, h, nullptr, NN, 96, 128, 1, 1);
  cvt_bf16<<<(NN * HID / 4 + 255) / 256, 256, 0, stream>>>(h, hbf, NN * HID / 4);

  for (int l = 0; l < NL; ++l) {
    gate_cb<<<1, 128, 0, stream>>>(relgate + l * NR, convb + (size_t)l * NR * HID, gate, cb);
    hipMemsetAsync(hmsg, 0, (size_t)NN * HID * 4, stream);
    for (int r = 0; r < NR; ++r) {
      int lr = l * NR + r;
      for (int hp = 0; hp < passes; ++hp) {
        int hpBase = hp * HP;
        const unsigned short* wl = linlwb + ((size_t)lr * 512 + hpBase * 128) * 128;
        const unsigned short* wr = linrwb + ((size_t)lr * 512 + hpBase * 128) * 128;
        const float* bl = linlb + (size_t)lr * 512 + hpBase * 128;
        const float* br = linrb + (size_t)lr * 512 + hpBase * 128;
        gemm_rows<<<NB * HP, 256, 0, stream>>>(hbf, srclist + (size_t)r * NN, nsrc + r * 16,
                                               wl, bl, xlb, 128, stride, HP);
        gemm_rows<<<NB * HP, 256, 0, stream>>>(hbf, hotlist + (size_t)r * NN, nhot + r * 16,
                                               wr, br, xrh, 128, stride, HP);
        edge_solo<<<2048, 256, 0, stream>>>(solosrc, solodst, nsolo, xlb, hmsg,
                                            gate, r, HP, stride);
        edge_hot<<<4096, 256, 0, stream>>>(
            csroff, rsrcx, eacsr, relemb + (size_t)lr * RED,
            linew + ((size_t)lr * 512 + hpBase * 128) * 24,
            attw + (size_t)lr * 512 + hpBase * 128,
            xlb, xrh, hotlist, nhot, hmsg, gate, r, HP, stride);
      }
    }
    add_ln<<<(NN + 3) / 4, 256, 0, stream>>>(h, hmsg, cb, n1w + l * HID, n1b + l * HID, hbf, NN);
    gemm_bf16<<<8 * RPX * 2, 256, 0, stream>>>(hbf, f1wb + (size_t)l * 256 * 128,
                                               f1bias + (size_t)l * 256, nullptr, f1buf,
                                               NN, 128, 256, 1, 2);
    gemm_bf16<<<8 * RPX, 256, 0, stream>>>(f1buf, f2wb + (size_t)l * 128 * 256,
                                           f2bias + (size_t)l * 128, hmsg, nullptr,
                                           NN, 256, 128, 0, 1);
    add_ln<<<(NN + 3) / 4, 256, 0, stream>>>(h, hmsg, nullptr, n2w + l * HID, n2b + l * HID, hbf, NN);
  }

  group_bounds<<<1, 128, 0, stream>>>(batch, gstart);
  readout_part2<<<dim3(NG, 8), 128, 0, stream>>>(h, gstart, psum, pmax);
  readout_final<<<NG, 256, 0, stream>>>(gstart, psum, pmax, rnw, rnb, g);
  kan1_part<<<dim3(NG, 8), 128, 0, stream>>>(g, bw1, sw1, sc1, grid1, zpart);
  kan2<<<NG, 128, 0, stream>>>(zpart, bw2, sw2, sc2, grid2, out);
}

// Round 15
// 1512.499 us; speedup vs baseline: 1.0970x; 1.0970x over previous
//
#include <hip/hip_runtime.h>
#include <math.h>

#define NN 50000
#define NE 120000
#define FN 64
#define NEA 16
#define NR 4
#define NH 4
#define HID 128
#define NL 3
#define IDE 32
#define RED 8
#define NG 64
#define NC 10
#define KH 128
#define FFH 256
#define NBIN (NR * NN)
#define SCAN_BLK ((NBIN + 1023) / 1024)

typedef short bf16x8 __attribute__((ext_vector_type(8)));
typedef float f32x4 __attribute__((ext_vector_type(4)));

__device__ __forceinline__ unsigned short f2b(float f) {
  unsigned u = __float_as_uint(f);
  unsigned r = (u + 0x7FFFu + ((u >> 16) & 1u)) >> 16;
  return (unsigned short)r;
}
__device__ __forceinline__ float b2f(unsigned short b) {
  return __uint_as_float((unsigned)b << 16);
}

__global__ void cvt_bf16(const float* __restrict__ s, unsigned short* __restrict__ d, int n4) {
  int i = blockIdx.x * blockDim.x + threadIdx.x;
  if (i >= n4) return;
  float4 v = ((const float4*)s)[i];
  ushort4 o;
  o.x = f2b(v.x); o.y = f2b(v.y); o.z = f2b(v.z); o.w = f2b(v.w);
  ((ushort4*)d)[i] = o;
}

// ---- GEMM core: 128x128 tile, optional A-row gather, LDS-staged bf16 epilogue ----
__device__ __forceinline__ void gemm_core(
    char* smem, const unsigned short* __restrict__ A, const int* __restrict__ rowlist,
    const unsigned short* __restrict__ W,
    const float* __restrict__ bias, float* __restrict__ Cf, unsigned short* __restrict__ Cb,
    int nrows, int K, int mout, int act, int rowBase, int colBase) {
  unsigned short (*As)[36] = (unsigned short (*)[36])smem;
  unsigned short (*Ws)[36] = (unsigned short (*)[36])(smem + 9216);
  int t = threadIdx.x;
  int lane = t & 63, w = t >> 6;
  int wm = w >> 1, wn = w & 1;
  int q = lane >> 4, mr = lane & 15;
  f32x4 acc[4][4] = {};
  for (int k0 = 0; k0 < K; k0 += 32) {
#pragma unroll
    for (int half = 0; half < 2; ++half) {
      int c = t + half * 256;
      int row = c >> 2, c16 = c & 3;
      int gr = rowBase + row;
      bf16x8 av = {0, 0, 0, 0, 0, 0, 0, 0};
      if (gr < nrows) {
        int ar = rowlist ? rowlist[gr] : gr;
        av = *(const bf16x8*)(A + (size_t)ar * K + k0 + c16 * 8);
      }
      *(bf16x8*)&As[row][c16 * 8] = av;
      bf16x8 wv = *(const bf16x8*)(W + (size_t)(colBase + row) * K + k0 + c16 * 8);
      *(bf16x8*)&Ws[row][c16 * 8] = wv;
    }
    __syncthreads();
    bf16x8 af[4], bfr[4];
#pragma unroll
    for (int mt = 0; mt < 4; ++mt) af[mt] = *(const bf16x8*)&As[wm * 64 + mt * 16 + mr][q * 8];
#pragma unroll
    for (int nt = 0; nt < 4; ++nt) bfr[nt] = *(const bf16x8*)&Ws[wn * 64 + nt * 16 + mr][q * 8];
#pragma unroll
    for (int mt = 0; mt < 4; ++mt)
#pragma unroll
      for (int nt = 0; nt < 4; ++nt)
        acc[mt][nt] = __builtin_amdgcn_mfma_f32_16x16x32_bf16(af[mt], bfr[nt], acc[mt][nt], 0, 0, 0);
    __syncthreads();
  }
  if (Cb) {
    unsigned short (*Es)[136] = (unsigned short (*)[136])smem;
#pragma unroll
    for (int ph = 0; ph < 2; ++ph) {
      if (wm == ph) {
#pragma unroll
        for (int mt = 0; mt < 4; ++mt)
#pragma unroll
          for (int nt = 0; nt < 4; ++nt)
#pragma unroll
            for (int r = 0; r < 4; ++r) {
              float v = acc[mt][nt][r] + bias[colBase + wn * 64 + nt * 16 + mr];
              if (act) v = v / (1.f + expf(-v));
              Es[mt * 16 + q * 4 + r][wn * 64 + nt * 16 + mr] = f2b(v);
            }
      }
      __syncthreads();
      int rl = t >> 2, co = (t & 3) * 32;
      int grow = rowBase + ph * 64 + rl;
      if (grow < nrows) {
        unsigned short* dst = Cb + (size_t)grow * mout + colBase + co;
#pragma unroll
        for (int j = 0; j < 4; ++j)
          *(bf16x8*)(dst + j * 8) = *(const bf16x8*)&Es[rl][co + j * 8];
      }
      __syncthreads();
    }
  } else {
#pragma unroll
    for (int mt = 0; mt < 4; ++mt)
#pragma unroll
      for (int nt = 0; nt < 4; ++nt)
#pragma unroll
        for (int r = 0; r < 4; ++r) {
          int row = rowBase + wm * 64 + mt * 16 + q * 4 + r;
          int col = colBase + wn * 64 + nt * 16 + mr;
          if (row < nrows) {
            float v = acc[mt][nt][r] + bias[col];
            if (act) v = v / (1.f + expf(-v));
            Cf[(size_t)row * mout + col] = v;
          }
        }
  }
}

// XCD-aware full GEMM (dispatch is round-robin over 8 XCDs: bid&7 = XCD)
__global__ __launch_bounds__(256) void gemm_bf16(
    const unsigned short* __restrict__ A, const unsigned short* __restrict__ W,
    const float* __restrict__ bias, float* __restrict__ Cf, unsigned short* __restrict__ Cb,
    int nrows, int K, int mout, int act, int ncol) {
  __shared__ char smem[20480];
  int nbr = (nrows + 127) >> 7;
  int rpx = (nbr + 7) >> 3;
  int xcd = blockIdx.x & 7, j = blockIdx.x >> 3;
  int rowT = xcd * rpx + j / ncol;
  int cy = j - (j / ncol) * ncol;
  if (rowT >= nbr) return;
  gemm_core(smem, A, nullptr, W, bias, Cf, Cb, nrows, K, mout, act, rowT * 128, cy * 128);
}

// dual row-gather GEMM, XCD-swizzled (device-side counts). First grid half: list1/W1->C1.
__global__ __launch_bounds__(256) void gemm_rows2(
    const unsigned short* __restrict__ A,
    const int* __restrict__ list1, const int* __restrict__ n1p,
    const unsigned short* __restrict__ W1, const float* __restrict__ b1,
    unsigned short* __restrict__ C1,
    const int* __restrict__ list2, const int* __restrict__ n2p,
    const unsigned short* __restrict__ W2, const float* __restrict__ b2,
    unsigned short* __restrict__ C2,
    int K, int mout, int ncol) {
  __shared__ char smem[20480];
  int half = gridDim.x >> 1;
  int sel = (int)blockIdx.x >= half;
  int bid = sel ? (int)blockIdx.x - half : (int)blockIdx.x;
  int nrows = *(sel ? n2p : n1p);
  int nbr = (nrows + 127) >> 7;
  int rpx = (nbr + 7) >> 3;
  int xcd = bid & 7, j = bid >> 3;
  int jr = j / ncol, cy = j - jr * ncol;
  if (jr >= rpx) return;            // avoid cross-XCD tile duplication
  int rowT = xcd * rpx + jr;
  if (rowT >= nbr) return;
  gemm_core(smem, A, sel ? list2 : list1, sel ? W2 : W1, sel ? b2 : b1,
            nullptr, sel ? C2 : C1, nrows, K, mout, 0, rowT * 128, cy * 128);
}

__global__ void build_xin_bf(const float* __restrict__ x, const int* __restrict__ idtok,
                             const float* __restrict__ emb, unsigned short* __restrict__ xin) {
  int i = blockIdx.x * blockDim.x + threadIdx.x;
  if (i >= NN * 96) return;
  int n = i / 96, k = i - n * 96;
  float v = (k < FN) ? x[(size_t)n * FN + k] : emb[(size_t)idtok[n] * IDE + (k - FN)];
  xin[i] = f2b(v);
}

// ---- CSR by (rel, dst) ----
__global__ void hist_bin(const int* __restrict__ ei, const int* __restrict__ et,
                         int* __restrict__ bcnt) {
  int e = blockIdx.x * blockDim.x + threadIdx.x;
  if (e >= NE) return;
  atomicAdd(&bcnt[et[e] * NN + ei[NE + e]], 1);
}
// generic exclusive scan over NBIN ints (3 kernels)
__global__ __launch_bounds__(256) void scan1(const int* __restrict__ cnt,
                                             int* __restrict__ pos, int* __restrict__ bsum) {
  __shared__ int lds[256];
  int b = blockIdx.x, t = threadIdx.x;
  int base = b * 1024 + t * 4;
  int v[4];
#pragma unroll
  for (int j = 0; j < 4; ++j) v[j] = (base + j < NBIN) ? cnt[base + j] : 0;
  int tot = v[0] + v[1] + v[2] + v[3];
  lds[t] = tot;
  __syncthreads();
  for (int off = 1; off < 256; off <<= 1) {
    int x = (t >= off) ? lds[t - off] : 0;
    __syncthreads();
    lds[t] += x;
    __syncthreads();
  }
  if (t == 255) bsum[b] = lds[255];
  int run = lds[t] - tot;
#pragma unroll
  for (int j = 0; j < 4; ++j) {
    if (base + j < NBIN) pos[base + j] = run;
    run += v[j];
  }
}
__global__ __launch_bounds__(256) void scan2(int* __restrict__ bsum) {
  __shared__ int lds[256];
  int t = threadIdx.x;
  int v = (t < SCAN_BLK) ? bsum[t] : 0;
  lds[t] = v;
  __syncthreads();
  for (int off = 1; off < 256; off <<= 1) {
    int x = (t >= off) ? lds[t - off] : 0;
    __syncthreads();
    lds[t] += x;
    __syncthreads();
  }
  if (t < SCAN_BLK) bsum[t] = lds[t] - v;
}
__global__ void scan3(int* __restrict__ pos, const int* __restrict__ bsum,
                      const int* __restrict__ cnt) {
  int i = blockIdx.x * blockDim.x + threadIdx.x;
  if (i >= NBIN) return;
  pos[i] += bsum[i >> 10];
  if (i == NBIN - 1) pos[NBIN] = pos[i] + cnt[i];
}
__global__ void scatter_bin(const int* __restrict__ ei, const int* __restrict__ et,
                            const int* __restrict__ csroff, int* __restrict__ cur,
                            int* __restrict__ elist) {
  int e = blockIdx.x * blockDim.x + threadIdx.x;
  if (e >= NE) return;
  int bin = et[e] * NN + ei[NE + e];
  int p = atomicAdd(&cur[bin], 1);
  elist[csroff[bin] + p] = e;
}
// DETERMINISM: atomic scatter order varies call-to-call; sort each bin.
__global__ void sort_bins(const int* __restrict__ csroff, int* __restrict__ elist) {
  int b = blockIdx.x * blockDim.x + threadIdx.x;
  if (b >= NBIN) return;
  int s = csroff[b], e = csroff[b + 1];
  for (int i = s + 1; i < e; ++i) {
    int key = elist[i];
    int j = i - 1;
    while (j >= s && elist[j] > key) { elist[j + 1] = elist[j]; --j; }
    elist[j + 1] = key;
  }
}
__global__ void gather_edge(const int* __restrict__ ei, const int* __restrict__ elist,
                            const float* __restrict__ eattr,
                            int* __restrict__ rsrc, float* __restrict__ eacsr) {
  int p = blockIdx.x * blockDim.x + threadIdx.x;
  if (p >= NE) return;
  int e = elist[p];
  rsrc[p] = ei[e];
  const float4* s = (const float4*)(eattr + (size_t)e * NEA);
  float4* d = (float4*)(eacsr + (size_t)p * NEA);
#pragma unroll
  for (int j = 0; j < 4; ++j) d[j] = s[j];
}
// mark nodes that are a src of >=1 edge per rel (benign-race flag writes)
__global__ void mark_src(const int* __restrict__ ei, const int* __restrict__ et,
                         int* __restrict__ srcflag) {
  int e = blockIdx.x * blockDim.x + threadIdx.x;
  if (e >= NE) return;
  srcflag[et[e] * NN + ei[e]] = 1;
}
// ORDERED src compaction from scan positions (deterministic + sequential gather)
__global__ void build_src_o(const int* __restrict__ srcflag, const int* __restrict__ srcpos,
                            int* __restrict__ srclist, int* __restrict__ srcmap) {
  int b = blockIdx.x * blockDim.x + threadIdx.x;
  if (b >= NBIN) return;
  if (srcflag[b]) {
    int rel = b / NN;
    int pos = srcpos[b] - srcpos[rel * NN];
    srcmap[b] = pos;
    srclist[rel * NN + pos] = b - rel * NN;
  }
}
__global__ void fincnt(const int* __restrict__ srcpos, int* __restrict__ nsrc) {
  int r = threadIdx.x;
  if (r < NR) nsrc[r * 16] = srcpos[(r + 1) * NN] - srcpos[r * NN];
}
// remap CSR src ids -> dense xl row indices
__global__ void remap_rsrc(const int* __restrict__ csroff, const int* __restrict__ rsrc,
                           const int* __restrict__ srcmap, int* __restrict__ rsrcx) {
  int p = blockIdx.x * blockDim.x + threadIdx.x;
  if (p >= NE) return;
  int rel = (p >= csroff[NN]) + (p >= csroff[2 * NN]) + (p >= csroff[3 * NN]);
  rsrcx[p] = srcmap[rel * NN + rsrc[p]];
}
// per-rel solo (deg==1: mapped src + dst) + hot (deg>=2) lists (ballot; order
// nondeterministic but numerically neutral - each dst independent).
__global__ __launch_bounds__(256) void build_hot(
    const int* __restrict__ csroff, const int* __restrict__ rsrc,
    const int* __restrict__ srcmap,
    int* __restrict__ nsolo, int* __restrict__ nhot,
    int* __restrict__ solosrc, int* __restrict__ solodst, int* __restrict__ hotlist) {
  __shared__ int wsc[4][4], whc[4][4];
  __shared__ int sbase[4], hbase[4];
  int t = threadIdx.x, wave = t >> 6, lane = t & 63;
  int b = blockIdx.x * 256 + t;
  bool valid = b < NBIN;
  int cnt = 0, rel = 0, s = 0;
  if (valid) { s = csroff[b]; cnt = csroff[b + 1] - s; rel = b / NN; }
  bool solo = valid && cnt == 1;
  bool hot = valid && cnt >= 2;
#pragma unroll
  for (int rr = 0; rr < 4; ++rr) {
    unsigned long long ms = __ballot(solo && rel == rr);
    unsigned long long mh = __ballot(hot && rel == rr);
    if (lane == 0) { wsc[wave][rr] = __popcll(ms); whc[wave][rr] = __popcll(mh); }
  }
  __syncthreads();
  if (t < 4) {
    int ssum = wsc[0][t] + wsc[1][t] + wsc[2][t] + wsc[3][t];
    int hsum = whc[0][t] + whc[1][t] + whc[2][t] + whc[3][t];
    sbase[t] = ssum ? atomicAdd(&nsolo[t * 16], ssum) : 0;
    hbase[t] = hsum ? atomicAdd(&nhot[t * 16], hsum) : 0;
  }
  __syncthreads();
#pragma unroll
  for (int rr = 0; rr < 4; ++rr) {
    unsigned long long ms = __ballot(solo && rel == rr);
    if (solo && rel == rr) {
      int before = 0;
#pragma unroll
      for (int wv = 0; wv < 4; ++wv) if (wv < wave) before += wsc[wv][rr];
      int pos = sbase[rr] + before + __popcll(ms & ((1ull << lane) - 1ull));
      solosrc[rr * NN + pos] = srcmap[rr * NN + rsrc[s]];
      solodst[rr * NN + pos] = b - rr * NN;
    }
    unsigned long long mh = __ballot(hot && rel == rr);
    if (hot && rel == rr) {
      int before = 0;
#pragma unroll
      for (int wv = 0; wv < 4; ++wv) if (wv < wave) before += whc[wv][rr];
      int pos = hbase[rr] + before + __popcll(mh & ((1ull << lane) - 1ull));
      hotlist[rr * NN + pos] = b - rr * NN;
    }
  }
}

__global__ void gate_cb(const float* __restrict__ rg, const float* __restrict__ cbias,
                        float* __restrict__ gate, float* __restrict__ cb) {
  __shared__ float g[NR];
  int t = threadIdx.x;
  if (t == 0) {
    float mx = rg[0];
    for (int r = 1; r < NR; ++r) mx = fmaxf(mx, rg[r]);
    float s = 0.f, tmp[NR];
    for (int r = 0; r < NR; ++r) { tmp[r] = expf(rg[r] - mx); s += tmp[r]; }
    for (int r = 0; r < NR; ++r) { g[r] = tmp[r] / s; gate[r] = g[r]; }
  }
  __syncthreads();
  float c = 0.f;
  for (int r = 0; r < NR; ++r) c += g[r] * cbias[r * HID + t];
  cb[t] = c;
}

// ---- fused edge pass: blocks [0,soloB) do deg-1 (wave/dst, no sync);
// blocks [soloB, grid) do deg>=2 (block/dst, online softmax). Disjoint dsts. ----
__global__ __launch_bounds__(256) void edge_all(
    const int* __restrict__ solosrc, const int* __restrict__ solodst,
    const int* __restrict__ nsolo,
    const int* __restrict__ csroff, const int* __restrict__ rsrcx,
    const float* __restrict__ eacsr, const float* __restrict__ relembp,
    const float* __restrict__ wedgep, const float* __restrict__ attwp,
    const unsigned short* __restrict__ xlb, const unsigned short* __restrict__ xrh,
    const int* __restrict__ hotlist, const int* __restrict__ nhot,
    float* __restrict__ hmsg, const float* __restrict__ gate,
    int rel, int HP, int stride, int soloB) {
  __shared__ float lds[4][128];
  int wave = threadIdx.x >> 6, lane = threadIdx.x & 63;
  float g4 = gate[rel] * 0.25f;
  if ((int)blockIdx.x < soloB) {
    int nw = nsolo[rel * 16];
    for (int i = (int)blockIdx.x * 4 + wave; i < nw; i += soloB * 4) {
      int src = solosrc[rel * NN + i];
      int dst = solodst[rel * NN + i];
      const unsigned short* xp = xlb + (size_t)src * stride;
      float v0 = 0.f, v1 = 0.f;
      for (int h = 0; h < HP; ++h) {
        v0 += b2f(xp[h * 128 + lane]);
        v1 += b2f(xp[h * 128 + 64 + lane]);
      }
      hmsg[(size_t)dst * HID + lane] += g4 * v0;
      hmsg[(size_t)dst * HID + 64 + lane] += g4 * v1;
    }
    return;
  }
  int hotB = gridDim.x - soloB;
  int hb = (int)blockIdx.x - soloB;
  bool act = wave < HP;
  int hh = act ? wave : 0;
  float wreg[2][24], areg[2];
#pragma unroll
  for (int j = 0; j < 2; ++j) {
    int col = hh * 128 + j * 64 + lane;
    const float* wp = wedgep + (size_t)col * 24;
#pragma unroll
    for (int k = 0; k < 24; ++k) wreg[j][k] = wp[k];
    areg[j] = attwp[col];
  }
  float evr0 = 0.f, evr1 = 0.f;
#pragma unroll
  for (int k = 0; k < 8; ++k) {
    float rk = relembp[k];
    evr0 += rk * wreg[0][NEA + k];
    evr1 += rk * wreg[1][NEA + k];
  }
  int nh = nhot[rel * 16];
  for (int wi = hb; wi < nh; wi += hotB) {
    int dst = hotlist[rel * NN + wi];
    int s = csroff[rel * NN + dst], e = csroff[rel * NN + dst + 1];
    if (act) {
      const unsigned short* xrp = xrh + (size_t)wi * stride;
      float xr0 = b2f(xrp[hh * 128 + lane]);
      float xr1 = b2f(xrp[hh * 128 + 64 + lane]);
      float m = -3.4e38f, den = 0.f, acc0 = 0.f, acc1 = 0.f;
      for (int p = s; p < e; ++p) {
        int src = rsrcx[p];
        const float* eap = eacsr + (size_t)p * NEA;
        float er[NEA];
#pragma unroll
        for (int k = 0; k < NEA; ++k) er[k] = eap[k];
        float eev0 = evr0, eev1 = evr1;
#pragma unroll
        for (int k = 0; k < NEA; ++k) { eev0 += er[k] * wreg[0][k]; eev1 += er[k] * wreg[1][k]; }
        float xl0 = b2f(xlb[(size_t)src * stride + hh * 128 + lane]);
        float xl1 = b2f(xlb[(size_t)src * stride + hh * 128 + 64 + lane]);
        float s0 = xl0 + xr0 + eev0; s0 = (s0 > 0.f) ? s0 : 0.2f * s0;
        float s1 = xl1 + xr1 + eev1; s1 = (s1 > 0.f) ? s1 : 0.2f * s1;
        float lg = s0 * areg[0] + s1 * areg[1];
#pragma unroll
        for (int o = 32; o > 0; o >>= 1) lg += __shfl_xor(lg, o, 64);
        float mn = fmaxf(m, lg);
        float sc = expf(m - mn);
        float ex = expf(lg - mn);
        den = den * sc + ex;
        acc0 = acc0 * sc + ex * xl0;
        acc1 = acc1 * sc + ex * xl1;
        m = mn;
      }
      float w = g4 / den;
      lds[wave][lane] = acc0 * w;
      lds[wave][64 + lane] = acc1 * w;
    }
    __syncthreads();
    if (wave < 2) {
      int d = wave * 64 + lane;
      float v = 0.f;
      for (int h = 0; h < HP; ++h) v += lds[h][d];
      hmsg[(size_t)dst * HID + d] += v;
    }
    __syncthreads();
  }
}

// ---- h = layernorm(h + add (+ cb)); also emits bf16 copy ----
__global__ __launch_bounds__(256) void add_ln(
    float* __restrict__ h, const float* __restrict__ add, const float* __restrict__ cb,
    const float* __restrict__ w, const float* __restrict__ b,
    unsigned short* __restrict__ hbf, int nrows) {
  int wave = threadIdx.x >> 6, lane = threadIdx.x & 63;
  int row = blockIdx.x * 4 + wave;
  if (row >= nrows) return;
  size_t base = (size_t)row * HID;
  float x0 = h[base + lane] + add[base + lane];
  float x1 = h[base + 64 + lane] + add[base + 64 + lane];
  if (cb) { x0 += cb[lane]; x1 += cb[64 + lane]; }
  float s = x0 + x1;
#pragma unroll
  for (int o = 32; o > 0; o >>= 1) s += __shfl_xor(s, o, 64);
  float mean = s * (1.f / 128.f);
  float d0 = x0 - mean, d1 = x1 - mean;
  float v = d0 * d0 + d1 * d1;
#pragma unroll
  for (int o = 32; o > 0; o >>= 1) v += __shfl_xor(v, o, 64);
  float inv = 1.f / sqrtf(v * (1.f / 128.f) + 1e-5f);
  float y0 = d0 * inv * w[lane] + b[lane];
  float y1 = d1 * inv * w[64 + lane] + b[64 + lane];
  h[base + lane] = y0;
  h[base + 64 + lane] = y1;
  hbf[base + lane] = f2b(y0);
  hbf[base + 64 + lane] = f2b(y1);
}

// ---- readout: deterministic (binary-search bounds, fixed partial slots) ----
__global__ void group_bounds(const int* __restrict__ batch, int* __restrict__ gstart) {
  int g = threadIdx.x + blockIdx.x * blockDim.x;
  if (g > NG) return;
  int lo = 0, hi = NN;
  while (lo < hi) {
    int mid = (lo + hi) >> 1;
    if (batch[mid] < g) lo = mid + 1; else hi = mid;
  }
  gstart[g] = lo;
}
__global__ __launch_bounds__(128) void readout_part2(
    const float* __restrict__ h, const int* __restrict__ gstart,
    float* __restrict__ psum, float* __restrict__ pmax) {
  int g = blockIdx.x, s = blockIdx.y, t = threadIdx.x;
  int r0 = gstart[g], r1 = gstart[g + 1];
  float acc = 0.f, mx = -3.4e38f;
  for (int row = r0 + s; row < r1; row += 8) {
    float v = h[(size_t)row * HID + t];
    acc += v;
    mx = fmaxf(mx, v);
  }
  psum[((size_t)g * 8 + s) * HID + t] = acc;
  pmax[((size_t)g * 8 + s) * HID + t] = mx;
}
__global__ __launch_bounds__(256) void readout_final(
    const int* __restrict__ gstart, const float* __restrict__ psum,
    const float* __restrict__ pmax, const float* __restrict__ w,
    const float* __restrict__ b, float* __restrict__ g) {
  int bg = blockIdx.x, t = threadIdx.x;
  __shared__ float red[256];
  float c = fmaxf((float)(gstart[bg + 1] - gstart[bg]), 1.f);
  float x;
  if (t < HID) {
    float ssum = 0.f;
    for (int s = 0; s < 8; ++s) ssum += psum[((size_t)bg * 8 + s) * HID + t];
    x = ssum / c;
  } else {
    float mx = -3.4e38f;
    for (int s = 0; s < 8; ++s) mx = fmaxf(mx, pmax[((size_t)bg * 8 + s) * HID + (t - HID)]);
    x = mx;
  }
  red[t] = x;
  __syncthreads();
  for (int s = 128; s > 0; s >>= 1) {
    if (t < s) red[t] += red[t + s];
    __syncthreads();
  }
  float mean = red[0] * (1.f / 256.f);
  __syncthreads();
  float d = x - mean;
  red[t] = d * d;
  __syncthreads();
  for (int s = 128; s > 0; s >>= 1) {
    if (t < s) red[t] += red[t + s];
    __syncthreads();
  }
  float inv = 1.f / sqrtf(red[0] * (1.f / 256.f) + 1e-5f);
  g[(size_t)bg * 256 + t] = d * inv * w[t] + b[t];
}

__device__ __forceinline__ void bspline8(float x, const float* __restrict__ t,
                                         float* __restrict__ out) {
  float bs[11];
#pragma unroll
  for (int j = 0; j < 11; ++j) bs[j] = (x >= t[j] && x < t[j + 1]) ? 1.f : 0.f;
#pragma unroll
  for (int k = 1; k <= 3; ++k) {
    for (int j = 0; j < 11 - k; ++j) {
      bs[j] = (x - t[j]) / (t[j + k] - t[j]) * bs[j] +
              (t[j + k + 1] - x) / (t[j + k + 1] - t[j + 1]) * bs[j + 1];
    }
  }
#pragma unroll
  for (int j = 0; j < 8; ++j) out[j] = bs[j];
}

// ---- KAN1, K-chunked into fixed partial slots (deterministic) ----
__global__ __launch_bounds__(128) void kan1_part(
    const float* __restrict__ g, const float* __restrict__ bw,
    const float* __restrict__ sw, const float* __restrict__ sc,
    const float* __restrict__ grid, float* __restrict__ zpart) {
  int bg = blockIdx.x, ch = blockIdx.y, t = threadIdx.x;
  int base = ch * 32;
  __shared__ float B[32][8];
  __shared__ float sg[32];
  if (t < 32) {
    float x = g[(size_t)bg * 256 + base + t];
    sg[t] = x / (1.f + expf(-x));
    bspline8(x, grid + (size_t)(base + t) * 12, B[t]);
  }
  __syncthreads();
  float acc = 0.f;
  for (int i = 0; i < 32; ++i) {
    int col = base + i;
    acc += sg[i] * bw[(size_t)t * 256 + col];
    const float* swp = sw + ((size_t)t * 256 + col) * 8;
    float sp = 0.f;
#pragma unroll
    for (int k = 0; k < 8; ++k) sp += B[i][k] * swp[k];
    acc += sp * sc[(size_t)t * 256 + col];
  }
  zpart[((size_t)ch * NG + bg) * KH + t] = acc;
}

__global__ __launch_bounds__(128) void kan2(
    const float* __restrict__ zpart, const float* __restrict__ bw,
    const float* __restrict__ sw, const float* __restrict__ sc,
    const float* __restrict__ grid, float* __restrict__ out) {
  int bg = blockIdx.x, t = threadIdx.x;
  __shared__ float B[128][8];
  __shared__ float sz[128];
  float x = 0.f;
  for (int ch = 0; ch < 8; ++ch) x += zpart[((size_t)ch * NG + bg) * KH + t];
  sz[t] = x / (1.f + expf(-x));
  bspline8(x, grid + (size_t)t * 12, B[t]);
  __syncthreads();
  if (t < NC) {
    float acc = 0.f;
    for (int i = 0; i < 128; ++i) {
      acc += sz[i] * bw[(size_t)t * 128 + i];
      const float* swp = sw + ((size_t)t * 128 + i) * 8;
      float sp = 0.f;
#pragma unroll
      for (int k = 0; k < 8; ++k) sp += B[i][k] * swp[k];
      acc += sp * sc[(size_t)t * 128 + i];
    }
    out[(size_t)bg * NC + t] = acc;
  }
}

extern "C" void kernel_launch(void* const* d_in, const int* in_sizes, int n_in,
                              void* d_out, int out_size, void* d_ws, size_t ws_size,
                              hipStream_t stream) {
  const float* x       = (const float*)d_in[0];
  const float* eattr   = (const float*)d_in[1];
  const int*   idtok   = (const int*)d_in[2];
  const int*   ei      = (const int*)d_in[3];
  const int*   etype   = (const int*)d_in[4];
  const int*   batch   = (const int*)d_in[5];
  const float* idemb   = (const float*)d_in[6];
  const float* inw     = (const float*)d_in[7];
  const float* inb     = (const float*)d_in[8];
  const float* relemb  = (const float*)d_in[9];
  const float* linlw   = (const float*)d_in[10];
  const float* linlb   = (const float*)d_in[11];
  const float* linrw   = (const float*)d_in[12];
  const float* linrb   = (const float*)d_in[13];
  const float* linew   = (const float*)d_in[14];
  const float* attw    = (const float*)d_in[15];
  const float* convb   = (const float*)d_in[16];
  const float* relgate = (const float*)d_in[17];
  const float* n1w     = (const float*)d_in[18];
  const float* n1b     = (const float*)d_in[19];
  const float* n2w     = (const float*)d_in[20];
  const float* n2b     = (const float*)d_in[21];
  const float* f1w     = (const float*)d_in[22];
  const float* f1bias  = (const float*)d_in[23];
  const float* f2w     = (const float*)d_in[24];
  const float* f2bias  = (const float*)d_in[25];
  const float* rnw     = (const float*)d_in[26];
  const float* rnb     = (const float*)d_in[27];
  const float* bw1     = (const float*)d_in[28];
  const float* sw1     = (const float*)d_in[29];
  const float* sc1     = (const float*)d_in[30];
  const float* grid1   = (const float*)d_in[31];
  const float* bw2     = (const float*)d_in[32];
  const float* sw2     = (const float*)d_in[33];
  const float* sc2     = (const float*)d_in[34];
  const float* grid2   = (const float*)d_in[35];
  float* out = (float*)d_out;
  (void)in_sizes; (void)n_in; (void)out_size;

  auto needed = [](int HP) -> size_t {
    auto al = [](size_t b) { return (b + 255) & ~(size_t)255; };
    size_t o = 0;
    o += al((size_t)NN * HID * 4) * 2;            // h, hmsg
    o += al((size_t)NN * HID * 2);                // hbf
    o += al((size_t)NN * 128 * HP * 2) * 2;       // xlb, xrh
    o += al((size_t)NE * 4) * 3;                  // elist, rsrc, rsrcx
    o += al((size_t)NE * NEA * 4);                // eacsr
    o += al((size_t)NBIN * 8 + 8);                // bcnt+cur
    o += al((size_t)(NBIN + 1) * 4) * 2;          // csroff, srcpos
    o += al((size_t)SCAN_BLK * 4);                // bsum
    o += al((size_t)NR * NN * 4) * 4;             // hotlist, solosrc, solodst, srclist
    o += al((size_t)NBIN * 4) * 2;                // srcflag, srcmap
    o += al(1024);                                // padded counters
    o += al((size_t)NL * NR * 512 * 128 * 2) * 2; // linlwb, linrwb
    o += al((size_t)NL * 256 * 128 * 2) * 2;      // f1wb, f2wb
    o += al((size_t)128 * 96 * 2);                // inwb
    o += al(NR * 4) + al(HID * 4);
    o += al((size_t)(NG + 1) * 4);                // gstart
    o += al((size_t)NG * 8 * HID * 4) * 2;        // psum, pmax
    o += al((size_t)8 * NG * KH * 4);             // zpart
    o += al((size_t)NG * 256 * 4);                // g
    return o;
  };
  const int HP = (needed(4) <= ws_size) ? 4 : 2;
  const int passes = NH / HP;
  const int stride = HP * 128;

  char* p = (char*)d_ws;
  auto alloc = [&](size_t bytes) { void* q = (void*)p; p += (bytes + 255) & ~(size_t)255; return q; };
  float* h    = (float*)alloc((size_t)NN * HID * 4);
  float* hmsg = (float*)alloc((size_t)NN * HID * 4);
  unsigned short* hbf = (unsigned short*)alloc((size_t)NN * HID * 2);
  unsigned short* xlb = (unsigned short*)alloc((size_t)NN * 128 * HP * 2);
  unsigned short* xrh = (unsigned short*)alloc((size_t)NN * 128 * HP * 2);
  int* elist = (int*)alloc((size_t)NE * 4);
  int* rsrc  = (int*)alloc((size_t)NE * 4);
  int* rsrcx = (int*)alloc((size_t)NE * 4);
  float* eacsr = (float*)alloc((size_t)NE * NEA * 4);
  int* bcnt  = (int*)alloc((size_t)NBIN * 8 + 8);
  int* cur   = bcnt + NBIN;
  int* csroff = (int*)alloc((size_t)(NBIN + 1) * 4);
  int* srcpos = (int*)alloc((size_t)(NBIN + 1) * 4);
  int* bsum  = (int*)alloc((size_t)SCAN_BLK * 4);
  int* hotlist = (int*)alloc((size_t)NR * NN * 4);
  int* solosrc = (int*)alloc((size_t)NR * NN * 4);
  int* solodst = (int*)alloc((size_t)NR * NN * 4);
  int* srclist = (int*)alloc((size_t)NR * NN * 4);
  int* srcflag = (int*)alloc((size_t)NBIN * 4);
  int* srcmap  = (int*)alloc((size_t)NBIN * 4);
  int* cnts    = (int*)alloc(1024);  // nsolo[r*16], nhot[64+r*16], nsrc[128+r*16]
  int* nsolo   = cnts;
  int* nhot    = cnts + 64;
  int* nsrc    = cnts + 128;
  unsigned short* linlwb = (unsigned short*)alloc((size_t)NL * NR * 512 * 128 * 2);
  unsigned short* linrwb = (unsigned short*)alloc((size_t)NL * NR * 512 * 128 * 2);
  unsigned short* f1wb   = (unsigned short*)alloc((size_t)NL * 256 * 128 * 2);
  unsigned short* f2wb   = (unsigned short*)alloc((size_t)NL * 128 * 256 * 2);
  unsigned short* inwb   = (unsigned short*)alloc((size_t)128 * 96 * 2);
  float* gate = (float*)alloc(NR * 4);
  float* cb   = (float*)alloc(HID * 4);
  int* gstart = (int*)alloc((size_t)(NG + 1) * 4);
  float* psum = (float*)alloc((size_t)NG * 8 * HID * 4);
  float* pmax = (float*)alloc((size_t)NG * 8 * HID * 4);
  float* zpart = (float*)alloc((size_t)8 * NG * KH * 4);
  float* g = (float*)alloc((size_t)NG * 256 * 4);
  unsigned short* xinbf = xlb;
  unsigned short* f1buf = xlb;

  const int NB = (NN + 127) / 128;
  const int RPX = (NB + 7) / 8;

  {
    int n;
    n = NL * NR * 512 * 128 / 4;
    cvt_bf16<<<(n + 255) / 256, 256, 0, stream>>>(linlw, linlwb, n);
    cvt_bf16<<<(n + 255) / 256, 256, 0, stream>>>(linrw, linrwb, n);
    n = NL * 256 * 128 / 4;
    cvt_bf16<<<(n + 255) / 256, 256, 0, stream>>>(f1w, f1wb, n);
    cvt_bf16<<<(n + 255) / 256, 256, 0, stream>>>(f2w, f2wb, n);
    n = 128 * 96 / 4;
    cvt_bf16<<<(n + 255) / 256, 256, 0, stream>>>(inw, inwb, n);
  }

  hipMemsetAsync(bcnt, 0, (size_t)NBIN * 8 + 8, stream);
  hipMemsetAsync(srcflag, 0, (size_t)NBIN * 4, stream);
  hipMemsetAsync(cnts, 0, 1024, stream);
  hist_bin<<<(NE + 255) / 256, 256, 0, stream>>>(ei, etype, bcnt);
  scan1<<<SCAN_BLK, 256, 0, stream>>>(bcnt, csroff, bsum);
  scan2<<<1, 256, 0, stream>>>(bsum);
  scan3<<<(NBIN + 255) / 256, 256, 0, stream>>>(csroff, bsum, bcnt);
  scatter_bin<<<(NE + 255) / 256, 256, 0, stream>>>(ei, etype, csroff, cur, elist);
  sort_bins<<<(NBIN + 255) / 256, 256, 0, stream>>>(csroff, elist);
  gather_edge<<<(NE + 255) / 256, 256, 0, stream>>>(ei, elist, eattr, rsrc, eacsr);
  mark_src<<<(NE + 255) / 256, 256, 0, stream>>>(ei, etype, srcflag);
  scan1<<<SCAN_BLK, 256, 0, stream>>>(srcflag, srcpos, bsum);
  scan2<<<1, 256, 0, stream>>>(bsum);
  scan3<<<(NBIN + 255) / 256, 256, 0, stream>>>(srcpos, bsum, srcflag);
  build_src_o<<<(NBIN + 255) / 256, 256, 0, stream>>>(srcflag, srcpos, srclist, srcmap);
  fincnt<<<1, 64, 0, stream>>>(srcpos, nsrc);
  remap_rsrc<<<(NE + 255) / 256, 256, 0, stream>>>(csroff, rsrc, srcmap, rsrcx);
  build_hot<<<(NBIN + 255) / 256, 256, 0, stream>>>(csroff, rsrc, srcmap, nsolo, nhot,
                                                    solosrc, solodst, hotlist);

  build_xin_bf<<<(NN * 96 + 255) / 256, 256, 0, stream>>>(x, idtok, idemb, xinbf);
  gemm_bf16<<<8 * RPX, 256, 0, stream>>>(xinbf, inwb, inb, h, nullptr, NN, 96, 128, 1, 1);
  cvt_bf16<<<(NN * HID / 4 + 255) / 256, 256, 0, stream>>>(h, hbf, NN * HID / 4);

  for (int l = 0; l < NL; ++l) {
    gate_cb<<<1, 128, 0, stream>>>(relgate + l * NR, convb + (size_t)l * NR * HID, gate, cb);
    hipMemsetAsync(hmsg, 0, (size_t)NN * HID * 4, stream);
    for (int r = 0; r < NR; ++r) {
      int lr = l * NR + r;
      for (int hp = 0; hp < passes; ++hp) {
        int hpBase = hp * HP;
        const unsigned short* wl = linlwb + ((size_t)lr * 512 + hpBase * 128) * 128;
        const unsigned short* wr = linrwb + ((size_t)lr * 512 + hpBase * 128) * 128;
        const float* bl = linlb + (size_t)lr * 512 + hpBase * 128;
        const float* br = linrb + (size_t)lr * 512 + hpBase * 128;
        gemm_rows2<<<2 * 8 * RPX * HP, 256, 0, stream>>>(
            hbf,
            srclist + (size_t)r * NN, nsrc + r * 16, wl, bl, xlb,
            hotlist + (size_t)r * NN, nhot + r * 16, wr, br, xrh,
            128, stride, HP);
        edge_all<<<6144, 256, 0, stream>>>(
            solosrc, solodst, nsolo,
            csroff, rsrcx, eacsr, relemb + (size_t)lr * RED,
            linew + ((size_t)lr * 512 + hpBase * 128) * 24,
            attw + (size_t)lr * 512 + hpBase * 128,
            xlb, xrh, hotlist, nhot, hmsg, gate, r, HP, stride, 2048);
      }
    }
    add_ln<<<(NN + 3) / 4, 256, 0, stream>>>(h, hmsg, cb, n1w + l * HID, n1b + l * HID, hbf, NN);
    gemm_bf16<<<8 * RPX * 2, 256, 0, stream>>>(hbf, f1wb + (size_t)l * 256 * 128,
                                               f1bias + (size_t)l * 256, nullptr, f1buf,
                                               NN, 128, 256, 1, 2);
    gemm_bf16<<<8 * RPX, 256, 0, stream>>>(f1buf, f2wb + (size_t)l * 128 * 256,
                                           f2bias + (size_t)l * 128, hmsg, nullptr,
                                           NN, 256, 128, 0, 1);
    add_ln<<<(NN + 3) / 4, 256, 0, stream>>>(h, hmsg, nullptr, n2w + l * HID, n2b + l * HID, hbf, NN);
  }

  group_bounds<<<1, 128, 0, stream>>>(batch, gstart);
  readout_part2<<<dim3(NG, 8), 128, 0, stream>>>(h, gstart, psum, pmax);
  readout_final<<<NG, 256, 0, stream>>>(gstart, psum, pmax, rnw, rnb, g);
  kan1_part<<<dim3(NG, 8), 128, 0, stream>>>(g, bw1, sw1, sc1, grid1, zpart);
  kan2<<<NG, 128, 0, stream>>>(zpart, bw2, sw2, sc2, grid2, out);
}

// Round 16
// 1499.854 us; speedup vs baseline: 1.1062x; 1.0084x over previous
//
#include <hip/hip_runtime.h>
#include <math.h>

#define NN 50000
#define NE 120000
#define FN 64
#define NEA 16
#define NR 4
#define NH 4
#define HID 128
#define NL 3
#define IDE 32
#define RED 8
#define NG 64
#define NC 10
#define KH 128
#define FFH 256
#define NBIN (NR * NN)
#define SCAN_BLK ((NBIN + 1023) / 1024)

typedef short bf16x8 __attribute__((ext_vector_type(8)));
typedef float f32x4 __attribute__((ext_vector_type(4)));

__device__ __forceinline__ unsigned short f2b(float f) {
  unsigned u = __float_as_uint(f);
  unsigned r = (u + 0x7FFFu + ((u >> 16) & 1u)) >> 16;
  return (unsigned short)r;
}
__device__ __forceinline__ float b2f(unsigned short b) {
  return __uint_as_float((unsigned)b << 16);
}

__global__ void cvt_bf16(const float* __restrict__ s, unsigned short* __restrict__ d, int n4) {
  int i = blockIdx.x * blockDim.x + threadIdx.x;
  if (i >= n4) return;
  float4 v = ((const float4*)s)[i];
  ushort4 o;
  o.x = f2b(v.x); o.y = f2b(v.y); o.z = f2b(v.z); o.w = f2b(v.w);
  ((ushort4*)d)[i] = o;
}

// ---- GEMM core: 128x128 tile, DOUBLE-BUFFERED K-loop with register prefetch.
// K is short (3-8 iters) and blocks/CU few -> explicit pipeline hides glob latency.
// smem: As[2] @0/@9216, Ws[2] @18432/@27648 (pad 36 shorts: 2-way LDS, free).
// Epilogue: Cf-only -> f32 scalar; Cf+Cb -> both scalar; Cb-only -> LDS-staged bf16.
__device__ __forceinline__ void gemm_core(
    char* smem, const unsigned short* __restrict__ A, const int* __restrict__ rowlist,
    const unsigned short* __restrict__ W,
    const float* __restrict__ bias, float* __restrict__ Cf, unsigned short* __restrict__ Cb,
    int nrows, int K, int mout, int act, int rowBase, int colBase) {
  typedef unsigned short (*tile_t)[36];
  tile_t Asb[2] = { (tile_t)smem, (tile_t)(smem + 9216) };
  tile_t Wsb[2] = { (tile_t)(smem + 18432), (tile_t)(smem + 27648) };
  int t = threadIdx.x;
  int lane = t & 63, w = t >> 6;
  int wm = w >> 1, wn = w & 1;
  int q = lane >> 4, mr = lane & 15;
  // staging coords (2 chunks of 16B per thread per tile)
  int srow[2], sc16[2], sga[2];
  const unsigned short* aptr[2];
#pragma unroll
  for (int half = 0; half < 2; ++half) {
    int c = t + half * 256;
    srow[half] = c >> 2;
    sc16[half] = c & 3;
    int gr = rowBase + srow[half];
    sga[half] = gr < nrows;
    int ar = sga[half] ? (rowlist ? rowlist[gr] : gr) : 0;
    aptr[half] = A + (size_t)ar * K + sc16[half] * 8;
  }
  const unsigned short* wptr[2];
#pragma unroll
  for (int half = 0; half < 2; ++half)
    wptr[half] = W + (size_t)(colBase + srow[half]) * K + sc16[half] * 8;

  bf16x8 pa[2], pw[2];
  auto loadreg = [&](int k0) {
#pragma unroll
    for (int half = 0; half < 2; ++half) {
      bf16x8 z = {0, 0, 0, 0, 0, 0, 0, 0};
      pa[half] = sga[half] ? *(const bf16x8*)(aptr[half] + k0) : z;
      pw[half] = *(const bf16x8*)(wptr[half] + k0);
    }
  };
  auto storelds = [&](int buf) {
#pragma unroll
    for (int half = 0; half < 2; ++half) {
      *(bf16x8*)&Asb[buf][srow[half]][sc16[half] * 8] = pa[half];
      *(bf16x8*)&Wsb[buf][srow[half]][sc16[half] * 8] = pw[half];
    }
  };

  f32x4 acc[4][4] = {};
  int nk = K >> 5;
  loadreg(0);
  storelds(0);
  __syncthreads();
  for (int k = 0; k < nk; ++k) {
    if (k + 1 < nk) loadreg((k + 1) * 32);  // issue glob loads; no wait yet
    tile_t As = Asb[k & 1];
    tile_t Ws = Wsb[k & 1];
    bf16x8 af[4], bfr[4];
#pragma unroll
    for (int mt = 0; mt < 4; ++mt) af[mt] = *(const bf16x8*)&As[wm * 64 + mt * 16 + mr][q * 8];
#pragma unroll
    for (int nt = 0; nt < 4; ++nt) bfr[nt] = *(const bf16x8*)&Ws[wn * 64 + nt * 16 + mr][q * 8];
#pragma unroll
    for (int mt = 0; mt < 4; ++mt)
#pragma unroll
      for (int nt = 0; nt < 4; ++nt)
        acc[mt][nt] = __builtin_amdgcn_mfma_f32_16x16x32_bf16(af[mt], bfr[nt], acc[mt][nt], 0, 0, 0);
    if (k + 1 < nk) storelds((k + 1) & 1);  // vmcnt wait overlapped w/ MFMA above
    __syncthreads();
  }

  if (Cf) {
#pragma unroll
    for (int mt = 0; mt < 4; ++mt)
#pragma unroll
      for (int nt = 0; nt < 4; ++nt)
#pragma unroll
        for (int r = 0; r < 4; ++r) {
          int row = rowBase + wm * 64 + mt * 16 + q * 4 + r;
          int col = colBase + wn * 64 + nt * 16 + mr;
          if (row < nrows) {
            float v = acc[mt][nt][r] + bias[col];
            if (act) v = v / (1.f + expf(-v));
            Cf[(size_t)row * mout + col] = v;
            if (Cb) Cb[(size_t)row * mout + col] = f2b(v);
          }
        }
  } else {
    unsigned short (*Es)[136] = (unsigned short (*)[136])smem;
#pragma unroll
    for (int ph = 0; ph < 2; ++ph) {
      if (wm == ph) {
#pragma unroll
        for (int mt = 0; mt < 4; ++mt)
#pragma unroll
          for (int nt = 0; nt < 4; ++nt)
#pragma unroll
            for (int r = 0; r < 4; ++r) {
              float v = acc[mt][nt][r] + bias[colBase + wn * 64 + nt * 16 + mr];
              if (act) v = v / (1.f + expf(-v));
              Es[mt * 16 + q * 4 + r][wn * 64 + nt * 16 + mr] = f2b(v);
            }
      }
      __syncthreads();
      int rl = t >> 2, co = (t & 3) * 32;
      int grow = rowBase + ph * 64 + rl;
      if (grow < nrows) {
        unsigned short* dst = Cb + (size_t)grow * mout + colBase + co;
#pragma unroll
        for (int j = 0; j < 4; ++j)
          *(bf16x8*)(dst + j * 8) = *(const bf16x8*)&Es[rl][co + j * 8];
      }
      __syncthreads();
    }
  }
}

// XCD-aware full GEMM (dispatch is round-robin over 8 XCDs: bid&7 = XCD)
__global__ __launch_bounds__(256) void gemm_bf16(
    const unsigned short* __restrict__ A, const unsigned short* __restrict__ W,
    const float* __restrict__ bias, float* __restrict__ Cf, unsigned short* __restrict__ Cb,
    int nrows, int K, int mout, int act, int ncol) {
  __shared__ char smem[36864];
  int nbr = (nrows + 127) >> 7;
  int rpx = (nbr + 7) >> 3;
  int xcd = blockIdx.x & 7, j = blockIdx.x >> 3;
  int rowT = xcd * rpx + j / ncol;
  int cy = j - (j / ncol) * ncol;
  if (rowT >= nbr) return;
  gemm_core(smem, A, nullptr, W, bias, Cf, Cb, nrows, K, mout, act, rowT * 128, cy * 128);
}

// dual row-gather GEMM, XCD-swizzled (device-side counts). First grid half: list1/W1->C1.
__global__ __launch_bounds__(256) void gemm_rows2(
    const unsigned short* __restrict__ A,
    const int* __restrict__ list1, const int* __restrict__ n1p,
    const unsigned short* __restrict__ W1, const float* __restrict__ b1,
    unsigned short* __restrict__ C1,
    const int* __restrict__ list2, const int* __restrict__ n2p,
    const unsigned short* __restrict__ W2, const float* __restrict__ b2,
    unsigned short* __restrict__ C2,
    int K, int mout, int ncol) {
  __shared__ char smem[36864];
  int half = gridDim.x >> 1;
  int sel = (int)blockIdx.x >= half;
  int bid = sel ? (int)blockIdx.x - half : (int)blockIdx.x;
  int nrows = *(sel ? n2p : n1p);
  int nbr = (nrows + 127) >> 7;
  int rpx = (nbr + 7) >> 3;
  int xcd = bid & 7, j = bid >> 3;
  int jr = j / ncol, cy = j - jr * ncol;
  if (jr >= rpx) return;
  int rowT = xcd * rpx + jr;
  if (rowT >= nbr) return;
  gemm_core(smem, A, sel ? list2 : list1, sel ? W2 : W1, sel ? b2 : b1,
            nullptr, sel ? C2 : C1, nrows, K, mout, 0, rowT * 128, cy * 128);
}

__global__ void build_xin_bf(const float* __restrict__ x, const int* __restrict__ idtok,
                             const float* __restrict__ emb, unsigned short* __restrict__ xin) {
  int i = blockIdx.x * blockDim.x + threadIdx.x;
  if (i >= NN * 96) return;
  int n = i / 96, k = i - n * 96;
  float v = (k < FN) ? x[(size_t)n * FN + k] : emb[(size_t)idtok[n] * IDE + (k - FN)];
  xin[i] = f2b(v);
}

// ---- CSR by (rel, dst) ----
__global__ void hist_bin(const int* __restrict__ ei, const int* __restrict__ et,
                         int* __restrict__ bcnt) {
  int e = blockIdx.x * blockDim.x + threadIdx.x;
  if (e >= NE) return;
  atomicAdd(&bcnt[et[e] * NN + ei[NE + e]], 1);
}
__global__ __launch_bounds__(256) void scan1(const int* __restrict__ cnt,
                                             int* __restrict__ pos, int* __restrict__ bsum) {
  __shared__ int lds[256];
  int b = blockIdx.x, t = threadIdx.x;
  int base = b * 1024 + t * 4;
  int v[4];
#pragma unroll
  for (int j = 0; j < 4; ++j) v[j] = (base + j < NBIN) ? cnt[base + j] : 0;
  int tot = v[0] + v[1] + v[2] + v[3];
  lds[t] = tot;
  __syncthreads();
  for (int off = 1; off < 256; off <<= 1) {
    int x = (t >= off) ? lds[t - off] : 0;
    __syncthreads();
    lds[t] += x;
    __syncthreads();
  }
  if (t == 255) bsum[b] = lds[255];
  int run = lds[t] - tot;
#pragma unroll
  for (int j = 0; j < 4; ++j) {
    if (base + j < NBIN) pos[base + j] = run;
    run += v[j];
  }
}
__global__ __launch_bounds__(256) void scan2(int* __restrict__ bsum) {
  __shared__ int lds[256];
  int t = threadIdx.x;
  int v = (t < SCAN_BLK) ? bsum[t] : 0;
  lds[t] = v;
  __syncthreads();
  for (int off = 1; off < 256; off <<= 1) {
    int x = (t >= off) ? lds[t - off] : 0;
    __syncthreads();
    lds[t] += x;
    __syncthreads();
  }
  if (t < SCAN_BLK) bsum[t] = lds[t] - v;
}
__global__ void scan3(int* __restrict__ pos, const int* __restrict__ bsum,
                      const int* __restrict__ cnt) {
  int i = blockIdx.x * blockDim.x + threadIdx.x;
  if (i >= NBIN) return;
  pos[i] += bsum[i >> 10];
  if (i == NBIN - 1) pos[NBIN] = pos[i] + cnt[i];
}
__global__ void scatter_bin(const int* __restrict__ ei, const int* __restrict__ et,
                            const int* __restrict__ csroff, int* __restrict__ cur,
                            int* __restrict__ elist) {
  int e = blockIdx.x * blockDim.x + threadIdx.x;
  if (e >= NE) return;
  int bin = et[e] * NN + ei[NE + e];
  int p = atomicAdd(&cur[bin], 1);
  elist[csroff[bin] + p] = e;
}
// DETERMINISM: atomic scatter order varies call-to-call; sort each bin.
__global__ void sort_bins(const int* __restrict__ csroff, int* __restrict__ elist) {
  int b = blockIdx.x * blockDim.x + threadIdx.x;
  if (b >= NBIN) return;
  int s = csroff[b], e = csroff[b + 1];
  for (int i = s + 1; i < e; ++i) {
    int key = elist[i];
    int j = i - 1;
    while (j >= s && elist[j] > key) { elist[j + 1] = elist[j]; --j; }
    elist[j + 1] = key;
  }
}
__global__ void gather_edge(const int* __restrict__ ei, const int* __restrict__ elist,
                            const float* __restrict__ eattr,
                            int* __restrict__ rsrc, float* __restrict__ eacsr) {
  int p = blockIdx.x * blockDim.x + threadIdx.x;
  if (p >= NE) return;
  int e = elist[p];
  rsrc[p] = ei[e];
  const float4* s = (const float4*)(eattr + (size_t)e * NEA);
  float4* d = (float4*)(eacsr + (size_t)p * NEA);
#pragma unroll
  for (int j = 0; j < 4; ++j) d[j] = s[j];
}
__global__ void mark_src(const int* __restrict__ ei, const int* __restrict__ et,
                         int* __restrict__ srcflag) {
  int e = blockIdx.x * blockDim.x + threadIdx.x;
  if (e >= NE) return;
  srcflag[et[e] * NN + ei[e]] = 1;
}
// ORDERED src compaction from scan positions (deterministic + sequential gather)
__global__ void build_src_o(const int* __restrict__ srcflag, const int* __restrict__ srcpos,
                            int* __restrict__ srclist, int* __restrict__ srcmap) {
  int b = blockIdx.x * blockDim.x + threadIdx.x;
  if (b >= NBIN) return;
  if (srcflag[b]) {
    int rel = b / NN;
    int pos = srcpos[b] - srcpos[rel * NN];
    srcmap[b] = pos;
    srclist[rel * NN + pos] = b - rel * NN;
  }
}
__global__ void fincnt(const int* __restrict__ srcpos, int* __restrict__ nsrc) {
  int r = threadIdx.x;
  if (r < NR) nsrc[r * 16] = srcpos[(r + 1) * NN] - srcpos[r * NN];
}
__global__ void remap_rsrc(const int* __restrict__ csroff, const int* __restrict__ rsrc,
                           const int* __restrict__ srcmap, int* __restrict__ rsrcx) {
  int p = blockIdx.x * blockDim.x + threadIdx.x;
  if (p >= NE) return;
  int rel = (p >= csroff[NN]) + (p >= csroff[2 * NN]) + (p >= csroff[3 * NN]);
  rsrcx[p] = srcmap[rel * NN + rsrc[p]];
}
// per-rel solo (deg==1: mapped src + dst) + hot (deg>=2) lists.
__global__ __launch_bounds__(256) void build_hot(
    const int* __restrict__ csroff, const int* __restrict__ rsrc,
    const int* __restrict__ srcmap,
    int* __restrict__ nsolo, int* __restrict__ nhot,
    int* __restrict__ solosrc, int* __restrict__ solodst, int* __restrict__ hotlist) {
  __shared__ int wsc[4][4], whc[4][4];
  __shared__ int sbase[4], hbase[4];
  int t = threadIdx.x, wave = t >> 6, lane = t & 63;
  int b = blockIdx.x * 256 + t;
  bool valid = b < NBIN;
  int cnt = 0, rel = 0, s = 0;
  if (valid) { s = csroff[b]; cnt = csroff[b + 1] - s; rel = b / NN; }
  bool solo = valid && cnt == 1;
  bool hot = valid && cnt >= 2;
#pragma unroll
  for (int rr = 0; rr < 4; ++rr) {
    unsigned long long ms = __ballot(solo && rel == rr);
    unsigned long long mh = __ballot(hot && rel == rr);
    if (lane == 0) { wsc[wave][rr] = __popcll(ms); whc[wave][rr] = __popcll(mh); }
  }
  __syncthreads();
  if (t < 4) {
    int ssum = wsc[0][t] + wsc[1][t] + wsc[2][t] + wsc[3][t];
    int hsum = whc[0][t] + whc[1][t] + whc[2][t] + whc[3][t];
    sbase[t] = ssum ? atomicAdd(&nsolo[t * 16], ssum) : 0;
    hbase[t] = hsum ? atomicAdd(&nhot[t * 16], hsum) : 0;
  }
  __syncthreads();
#pragma unroll
  for (int rr = 0; rr < 4; ++rr) {
    unsigned long long ms = __ballot(solo && rel == rr);
    if (solo && rel == rr) {
      int before = 0;
#pragma unroll
      for (int wv = 0; wv < 4; ++wv) if (wv < wave) before += wsc[wv][rr];
      int pos = sbase[rr] + before + __popcll(ms & ((1ull << lane) - 1ull));
      solosrc[rr * NN + pos] = srcmap[rr * NN + rsrc[s]];
      solodst[rr * NN + pos] = b - rr * NN;
    }
    unsigned long long mh = __ballot(hot && rel == rr);
    if (hot && rel == rr) {
      int before = 0;
#pragma unroll
      for (int wv = 0; wv < 4; ++wv) if (wv < wave) before += whc[wv][rr];
      int pos = hbase[rr] + before + __popcll(mh & ((1ull << lane) - 1ull));
      hotlist[rr * NN + pos] = b - rr * NN;
    }
  }
}

__global__ void gate_cb(const float* __restrict__ rg, const float* __restrict__ cbias,
                        float* __restrict__ gate, float* __restrict__ cb) {
  __shared__ float g[NR];
  int t = threadIdx.x;
  if (t == 0) {
    float mx = rg[0];
    for (int r = 1; r < NR; ++r) mx = fmaxf(mx, rg[r]);
    float s = 0.f, tmp[NR];
    for (int r = 0; r < NR; ++r) { tmp[r] = expf(rg[r] - mx); s += tmp[r]; }
    for (int r = 0; r < NR; ++r) { g[r] = tmp[r] / s; gate[r] = g[r]; }
  }
  __syncthreads();
  float c = 0.f;
  for (int r = 0; r < NR; ++r) c += g[r] * cbias[r * HID + t];
  cb[t] = c;
}

// ---- fused edge pass: blocks [0,soloB) deg-1 (wave/dst); rest deg>=2 (block/dst) ----
__global__ __launch_bounds__(256) void edge_all(
    const int* __restrict__ solosrc, const int* __restrict__ solodst,
    const int* __restrict__ nsolo,
    const int* __restrict__ csroff, const int* __restrict__ rsrcx,
    const float* __restrict__ eacsr, const float* __restrict__ relembp,
    const float* __restrict__ wedgep, const float* __restrict__ attwp,
    const unsigned short* __restrict__ xlb, const unsigned short* __restrict__ xrh,
    const int* __restrict__ hotlist, const int* __restrict__ nhot,
    float* __restrict__ hmsg, const float* __restrict__ gate,
    int rel, int HP, int stride, int soloB) {
  __shared__ float lds[4][128];
  int wave = threadIdx.x >> 6, lane = threadIdx.x & 63;
  float g4 = gate[rel] * 0.25f;
  if ((int)blockIdx.x < soloB) {
    int nw = nsolo[rel * 16];
    for (int i = (int)blockIdx.x * 4 + wave; i < nw; i += soloB * 4) {
      int src = solosrc[rel * NN + i];
      int dst = solodst[rel * NN + i];
      const unsigned short* xp = xlb + (size_t)src * stride;
      float v0 = 0.f, v1 = 0.f;
      for (int h = 0; h < HP; ++h) {
        v0 += b2f(xp[h * 128 + lane]);
        v1 += b2f(xp[h * 128 + 64 + lane]);
      }
      hmsg[(size_t)dst * HID + lane] += g4 * v0;
      hmsg[(size_t)dst * HID + 64 + lane] += g4 * v1;
    }
    return;
  }
  int hotB = gridDim.x - soloB;
  int hb = (int)blockIdx.x - soloB;
  bool act = wave < HP;
  int hh = act ? wave : 0;
  float wreg[2][24], areg[2];
#pragma unroll
  for (int j = 0; j < 2; ++j) {
    int col = hh * 128 + j * 64 + lane;
    const float* wp = wedgep + (size_t)col * 24;
#pragma unroll
    for (int k = 0; k < 24; ++k) wreg[j][k] = wp[k];
    areg[j] = attwp[col];
  }
  float evr0 = 0.f, evr1 = 0.f;
#pragma unroll
  for (int k = 0; k < 8; ++k) {
    float rk = relembp[k];
    evr0 += rk * wreg[0][NEA + k];
    evr1 += rk * wreg[1][NEA + k];
  }
  int nh = nhot[rel * 16];
  for (int wi = hb; wi < nh; wi += hotB) {
    int dst = hotlist[rel * NN + wi];
    int s = csroff[rel * NN + dst], e = csroff[rel * NN + dst + 1];
    if (act) {
      const unsigned short* xrp = xrh + (size_t)wi * stride;
      float xr0 = b2f(xrp[hh * 128 + lane]);
      float xr1 = b2f(xrp[hh * 128 + 64 + lane]);
      float m = -3.4e38f, den = 0.f, acc0 = 0.f, acc1 = 0.f;
      for (int p = s; p < e; ++p) {
        int src = rsrcx[p];
        const float* eap = eacsr + (size_t)p * NEA;
        float er[NEA];
#pragma unroll
        for (int k = 0; k < NEA; ++k) er[k] = eap[k];
        float eev0 = evr0, eev1 = evr1;
#pragma unroll
        for (int k = 0; k < NEA; ++k) { eev0 += er[k] * wreg[0][k]; eev1 += er[k] * wreg[1][k]; }
        float xl0 = b2f(xlb[(size_t)src * stride + hh * 128 + lane]);
        float xl1 = b2f(xlb[(size_t)src * stride + hh * 128 + 64 + lane]);
        float s0 = xl0 + xr0 + eev0; s0 = (s0 > 0.f) ? s0 : 0.2f * s0;
        float s1 = xl1 + xr1 + eev1; s1 = (s1 > 0.f) ? s1 : 0.2f * s1;
        float lg = s0 * areg[0] + s1 * areg[1];
#pragma unroll
        for (int o = 32; o > 0; o >>= 1) lg += __shfl_xor(lg, o, 64);
        float mn = fmaxf(m, lg);
        float sc = expf(m - mn);
        float ex = expf(lg - mn);
        den = den * sc + ex;
        acc0 = acc0 * sc + ex * xl0;
        acc1 = acc1 * sc + ex * xl1;
        m = mn;
      }
      float w = g4 / den;
      lds[wave][lane] = acc0 * w;
      lds[wave][64 + lane] = acc1 * w;
    }
    __syncthreads();
    if (wave < 2) {
      int d = wave * 64 + lane;
      float v = 0.f;
      for (int h = 0; h < HP; ++h) v += lds[h][d];
      hmsg[(size_t)dst * HID + d] += v;
    }
    __syncthreads();
  }
}

// ---- h = layernorm(h + add (+ cb)); also emits bf16 copy ----
__global__ __launch_bounds__(256) void add_ln(
    float* __restrict__ h, const float* __restrict__ add, const float* __restrict__ cb,
    const float* __restrict__ w, const float* __restrict__ b,
    unsigned short* __restrict__ hbf, int nrows) {
  int wave = threadIdx.x >> 6, lane = threadIdx.x & 63;
  int row = blockIdx.x * 4 + wave;
  if (row >= nrows) return;
  size_t base = (size_t)row * HID;
  float x0 = h[base + lane] + add[base + lane];
  float x1 = h[base + 64 + lane] + add[base + 64 + lane];
  if (cb) { x0 += cb[lane]; x1 += cb[64 + lane]; }
  float s = x0 + x1;
#pragma unroll
  for (int o = 32; o > 0; o >>= 1) s += __shfl_xor(s, o, 64);
  float mean = s * (1.f / 128.f);
  float d0 = x0 - mean, d1 = x1 - mean;
  float v = d0 * d0 + d1 * d1;
#pragma unroll
  for (int o = 32; o > 0; o >>= 1) v += __shfl_xor(v, o, 64);
  float inv = 1.f / sqrtf(v * (1.f / 128.f) + 1e-5f);
  float y0 = d0 * inv * w[lane] + b[lane];
  float y1 = d1 * inv * w[64 + lane] + b[64 + lane];
  h[base + lane] = y0;
  h[base + 64 + lane] = y1;
  hbf[base + lane] = f2b(y0);
  hbf[base + 64 + lane] = f2b(y1);
}

// ---- readout: deterministic ----
__global__ void group_bounds(const int* __restrict__ batch, int* __restrict__ gstart) {
  int g = threadIdx.x + blockIdx.x * blockDim.x;
  if (g > NG) return;
  int lo = 0, hi = NN;
  while (lo < hi) {
    int mid = (lo + hi) >> 1;
    if (batch[mid] < g) lo = mid + 1; else hi = mid;
  }
  gstart[g] = lo;
}
__global__ __launch_bounds__(128) void readout_part2(
    const float* __restrict__ h, const int* __restrict__ gstart,
    float* __restrict__ psum, float* __restrict__ pmax) {
  int g = blockIdx.x, s = blockIdx.y, t = threadIdx.x;
  int r0 = gstart[g], r1 = gstart[g + 1];
  float acc = 0.f, mx = -3.4e38f;
  for (int row = r0 + s; row < r1; row += 8) {
    float v = h[(size_t)row * HID + t];
    acc += v;
    mx = fmaxf(mx, v);
  }
  psum[((size_t)g * 8 + s) * HID + t] = acc;
  pmax[((size_t)g * 8 + s) * HID + t] = mx;
}
__global__ __launch_bounds__(256) void readout_final(
    const int* __restrict__ gstart, const float* __restrict__ psum,
    const float* __restrict__ pmax, const float* __restrict__ w,
    const float* __restrict__ b, float* __restrict__ g) {
  int bg = blockIdx.x, t = threadIdx.x;
  __shared__ float red[256];
  float c = fmaxf((float)(gstart[bg + 1] - gstart[bg]), 1.f);
  float x;
  if (t < HID) {
    float ssum = 0.f;
    for (int s = 0; s < 8; ++s) ssum += psum[((size_t)bg * 8 + s) * HID + t];
    x = ssum / c;
  } else {
    float mx = -3.4e38f;
    for (int s = 0; s < 8; ++s) mx = fmaxf(mx, pmax[((size_t)bg * 8 + s) * HID + (t - HID)]);
    x = mx;
  }
  red[t] = x;
  __syncthreads();
  for (int s = 128; s > 0; s >>= 1) {
    if (t < s) red[t] += red[t + s];
    __syncthreads();
  }
  float mean = red[0] * (1.f / 256.f);
  __syncthreads();
  float d = x - mean;
  red[t] = d * d;
  __syncthreads();
  for (int s = 128; s > 0; s >>= 1) {
    if (t < s) red[t] += red[t + s];
    __syncthreads();
  }
  float inv = 1.f / sqrtf(red[0] * (1.f / 256.f) + 1e-5f);
  g[(size_t)bg * 256 + t] = d * inv * w[t] + b[t];
}

__device__ __forceinline__ void bspline8(float x, const float* __restrict__ t,
                                         float* __restrict__ out) {
  float bs[11];
#pragma unroll
  for (int j = 0; j < 11; ++j) bs[j] = (x >= t[j] && x < t[j + 1]) ? 1.f : 0.f;
#pragma unroll
  for (int k = 1; k <= 3; ++k) {
    for (int j = 0; j < 11 - k; ++j) {
      bs[j] = (x - t[j]) / (t[j + k] - t[j]) * bs[j] +
              (t[j + k + 1] - x) / (t[j + k + 1] - t[j + 1]) * bs[j + 1];
    }
  }
#pragma unroll
  for (int j = 0; j < 8; ++j) out[j] = bs[j];
}

// ---- KAN1, K-chunked into fixed partial slots (deterministic) ----
__global__ __launch_bounds__(128) void kan1_part(
    const float* __restrict__ g, const float* __restrict__ bw,
    const float* __restrict__ sw, const float* __restrict__ sc,
    const float* __restrict__ grid, float* __restrict__ zpart) {
  int bg = blockIdx.x, ch = blockIdx.y, t = threadIdx.x;
  int base = ch * 32;
  __shared__ float B[32][8];
  __shared__ float sg[32];
  if (t < 32) {
    float x = g[(size_t)bg * 256 + base + t];
    sg[t] = x / (1.f + expf(-x));
    bspline8(x, grid + (size_t)(base + t) * 12, B[t]);
  }
  __syncthreads();
  float acc = 0.f;
  for (int i = 0; i < 32; ++i) {
    int col = base + i;
    acc += sg[i] * bw[(size_t)t * 256 + col];
    const float* swp = sw + ((size_t)t * 256 + col) * 8;
    float sp = 0.f;
#pragma unroll
    for (int k = 0; k < 8; ++k) sp += B[i][k] * swp[k];
    acc += sp * sc[(size_t)t * 256 + col];
  }
  zpart[((size_t)ch * NG + bg) * KH + t] = acc;
}

__global__ __launch_bounds__(128) void kan2(
    const float* __restrict__ zpart, const float* __restrict__ bw,
    const float* __restrict__ sw, const float* __restrict__ sc,
    const float* __restrict__ grid, float* __restrict__ out) {
  int bg = blockIdx.x, t = threadIdx.x;
  __shared__ float B[128][8];
  __shared__ float sz[128];
  float x = 0.f;
  for (int ch = 0; ch < 8; ++ch) x += zpart[((size_t)ch * NG + bg) * KH + t];
  sz[t] = x / (1.f + expf(-x));
  bspline8(x, grid + (size_t)t * 12, B[t]);
  __syncthreads();
  if (t < NC) {
    float acc = 0.f;
    for (int i = 0; i < 128; ++i) {
      acc += sz[i] * bw[(size_t)t * 128 + i];
      const float* swp = sw + ((size_t)t * 128 + i) * 8;
      float sp = 0.f;
#pragma unroll
      for (int k = 0; k < 8; ++k) sp += B[i][k] * swp[k];
      acc += sp * sc[(size_t)t * 128 + i];
    }
    out[(size_t)bg * NC + t] = acc;
  }
}

extern "C" void kernel_launch(void* const* d_in, const int* in_sizes, int n_in,
                              void* d_out, int out_size, void* d_ws, size_t ws_size,
                              hipStream_t stream) {
  const float* x       = (const float*)d_in[0];
  const float* eattr   = (const float*)d_in[1];
  const int*   idtok   = (const int*)d_in[2];
  const int*   ei      = (const int*)d_in[3];
  const int*   etype   = (const int*)d_in[4];
  const int*   batch   = (const int*)d_in[5];
  const float* idemb   = (const float*)d_in[6];
  const float* inw     = (const float*)d_in[7];
  const float* inb     = (const float*)d_in[8];
  const float* relemb  = (const float*)d_in[9];
  const float* linlw   = (const float*)d_in[10];
  const float* linlb   = (const float*)d_in[11];
  const float* linrw   = (const float*)d_in[12];
  const float* linrb   = (const float*)d_in[13];
  const float* linew   = (const float*)d_in[14];
  const float* attw    = (const float*)d_in[15];
  const float* convb   = (const float*)d_in[16];
  const float* relgate = (const float*)d_in[17];
  const float* n1w     = (const float*)d_in[18];
  const float* n1b     = (const float*)d_in[19];
  const float* n2w     = (const float*)d_in[20];
  const float* n2b     = (const float*)d_in[21];
  const float* f1w     = (const float*)d_in[22];
  const float* f1bias  = (const float*)d_in[23];
  const float* f2w     = (const float*)d_in[24];
  const float* f2bias  = (const float*)d_in[25];
  const float* rnw     = (const float*)d_in[26];
  const float* rnb     = (const float*)d_in[27];
  const float* bw1     = (const float*)d_in[28];
  const float* sw1     = (const float*)d_in[29];
  const float* sc1     = (const float*)d_in[30];
  const float* grid1   = (const float*)d_in[31];
  const float* bw2     = (const float*)d_in[32];
  const float* sw2     = (const float*)d_in[33];
  const float* sc2     = (const float*)d_in[34];
  const float* grid2   = (const float*)d_in[35];
  float* out = (float*)d_out;
  (void)in_sizes; (void)n_in; (void)out_size;

  auto needed = [](int HP) -> size_t {
    auto al = [](size_t b) { return (b + 255) & ~(size_t)255; };
    size_t o = 0;
    o += al((size_t)NN * HID * 4) * 2;
    o += al((size_t)NN * HID * 2);
    o += al((size_t)NN * 128 * HP * 2) * 2;
    o += al((size_t)NE * 4) * 3;
    o += al((size_t)NE * NEA * 4);
    o += al((size_t)NBIN * 8 + 8);
    o += al((size_t)(NBIN + 1) * 4) * 2;
    o += al((size_t)SCAN_BLK * 4);
    o += al((size_t)NR * NN * 4) * 4;
    o += al((size_t)NBIN * 4) * 2;
    o += al(1024);
    o += al((size_t)NL * NR * 512 * 128 * 2) * 2;
    o += al((size_t)NL * 256 * 128 * 2) * 2;
    o += al((size_t)128 * 96 * 2);
    o += al(NR * 4) + al(HID * 4);
    o += al((size_t)(NG + 1) * 4);
    o += al((size_t)NG * 8 * HID * 4) * 2;
    o += al((size_t)8 * NG * KH * 4);
    o += al((size_t)NG * 256 * 4);
    return o;
  };
  const int HP = (needed(4) <= ws_size) ? 4 : 2;
  const int passes = NH / HP;
  const int stride = HP * 128;

  char* p = (char*)d_ws;
  auto alloc = [&](size_t bytes) { void* q = (void*)p; p += (bytes + 255) & ~(size_t)255; return q; };
  float* h    = (float*)alloc((size_t)NN * HID * 4);
  float* hmsg = (float*)alloc((size_t)NN * HID * 4);
  unsigned short* hbf = (unsigned short*)alloc((size_t)NN * HID * 2);
  unsigned short* xlb = (unsigned short*)alloc((size_t)NN * 128 * HP * 2);
  unsigned short* xrh = (unsigned short*)alloc((size_t)NN * 128 * HP * 2);
  int* elist = (int*)alloc((size_t)NE * 4);
  int* rsrc  = (int*)alloc((size_t)NE * 4);
  int* rsrcx = (int*)alloc((size_t)NE * 4);
  float* eacsr = (float*)alloc((size_t)NE * NEA * 4);
  int* bcnt  = (int*)alloc((size_t)NBIN * 8 + 8);
  int* cur   = bcnt + NBIN;
  int* csroff = (int*)alloc((size_t)(NBIN + 1) * 4);
  int* srcpos = (int*)alloc((size_t)(NBIN + 1) * 4);
  int* bsum  = (int*)alloc((size_t)SCAN_BLK * 4);
  int* hotlist = (int*)alloc((size_t)NR * NN * 4);
  int* solosrc = (int*)alloc((size_t)NR * NN * 4);
  int* solodst = (int*)alloc((size_t)NR * NN * 4);
  int* srclist = (int*)alloc((size_t)NR * NN * 4);
  int* srcflag = (int*)alloc((size_t)NBIN * 4);
  int* srcmap  = (int*)alloc((size_t)NBIN * 4);
  int* cnts    = (int*)alloc(1024);
  int* nsolo   = cnts;
  int* nhot    = cnts + 64;
  int* nsrc    = cnts + 128;
  unsigned short* linlwb = (unsigned short*)alloc((size_t)NL * NR * 512 * 128 * 2);
  unsigned short* linrwb = (unsigned short*)alloc((size_t)NL * NR * 512 * 128 * 2);
  unsigned short* f1wb   = (unsigned short*)alloc((size_t)NL * 256 * 128 * 2);
  unsigned short* f2wb   = (unsigned short*)alloc((size_t)NL * 128 * 256 * 2);
  unsigned short* inwb   = (unsigned short*)alloc((size_t)128 * 96 * 2);
  float* gate = (float*)alloc(NR * 4);
  float* cb   = (float*)alloc(HID * 4);
  int* gstart = (int*)alloc((size_t)(NG + 1) * 4);
  float* psum = (float*)alloc((size_t)NG * 8 * HID * 4);
  float* pmax = (float*)alloc((size_t)NG * 8 * HID * 4);
  float* zpart = (float*)alloc((size_t)8 * NG * KH * 4);
  float* g = (float*)alloc((size_t)NG * 256 * 4);
  unsigned short* xinbf = xlb;
  unsigned short* f1buf = xlb;

  const int NB = (NN + 127) / 128;
  const int RPX = (NB + 7) / 8;

  {
    int n;
    n = NL * NR * 512 * 128 / 4;
    cvt_bf16<<<(n + 255) / 256, 256, 0, stream>>>(linlw, linlwb, n);
    cvt_bf16<<<(n + 255) / 256, 256, 0, stream>>>(linrw, linrwb, n);
    n = NL * 256 * 128 / 4;
    cvt_bf16<<<(n + 255) / 256, 256, 0, stream>>>(f1w, f1wb, n);
    cvt_bf16<<<(n + 255) / 256, 256, 0, stream>>>(f2w, f2wb, n);
    n = 128 * 96 / 4;
    cvt_bf16<<<(n + 255) / 256, 256, 0, stream>>>(inw, inwb, n);
  }

  hipMemsetAsync(bcnt, 0, (size_t)NBIN * 8 + 8, stream);
  hipMemsetAsync(srcflag, 0, (size_t)NBIN * 4, stream);
  hipMemsetAsync(cnts, 0, 1024, stream);
  hist_bin<<<(NE + 255) / 256, 256, 0, stream>>>(ei, etype, bcnt);
  scan1<<<SCAN_BLK, 256, 0, stream>>>(bcnt, csroff, bsum);
  scan2<<<1, 256, 0, stream>>>(bsum);
  scan3<<<(NBIN + 255) / 256, 256, 0, stream>>>(csroff, bsum, bcnt);
  scatter_bin<<<(NE + 255) / 256, 256, 0, stream>>>(ei, etype, csroff, cur, elist);
  sort_bins<<<(NBIN + 255) / 256, 256, 0, stream>>>(csroff, elist);
  gather_edge<<<(NE + 255) / 256, 256, 0, stream>>>(ei, elist, eattr, rsrc, eacsr);
  mark_src<<<(NE + 255) / 256, 256, 0, stream>>>(ei, etype, srcflag);
  scan1<<<SCAN_BLK, 256, 0, stream>>>(srcflag, srcpos, bsum);
  scan2<<<1, 256, 0, stream>>>(bsum);
  scan3<<<(NBIN + 255) / 256, 256, 0, stream>>>(srcpos, bsum, srcflag);
  build_src_o<<<(NBIN + 255) / 256, 256, 0, stream>>>(srcflag, srcpos, srclist, srcmap);
  fincnt<<<1, 64, 0, stream>>>(srcpos, nsrc);
  remap_rsrc<<<(NE + 255) / 256, 256, 0, stream>>>(csroff, rsrc, srcmap, rsrcx);
  build_hot<<<(NBIN + 255) / 256, 256, 0, stream>>>(csroff, rsrc, srcmap, nsolo, nhot,
                                                    solosrc, solodst, hotlist);

  build_xin_bf<<<(NN * 96 + 255) / 256, 256, 0, stream>>>(x, idtok, idemb, xinbf);
  // dual-output epilogue: h (f32) + hbf (bf16) in one pass
  gemm_bf16<<<8 * RPX, 256, 0, stream>>>(xinbf, inwb, inb, h, hbf, NN, 96, 128, 1, 1);

  for (int l = 0; l < NL; ++l) {
    gate_cb<<<1, 128, 0, stream>>>(relgate + l * NR, convb + (size_t)l * NR * HID, gate, cb);
    hipMemsetAsync(hmsg, 0, (size_t)NN * HID * 4, stream);
    for (int r = 0; r < NR; ++r) {
      int lr = l * NR + r;
      for (int hp = 0; hp < passes; ++hp) {
        int hpBase = hp * HP;
        const unsigned short* wl = linlwb + ((size_t)lr * 512 + hpBase * 128) * 128;
        const unsigned short* wr = linrwb + ((size_t)lr * 512 + hpBase * 128) * 128;
        const float* bl = linlb + (size_t)lr * 512 + hpBase * 128;
        const float* br = linrb + (size_t)lr * 512 + hpBase * 128;
        gemm_rows2<<<2 * 8 * RPX * HP, 256, 0, stream>>>(
            hbf,
            srclist + (size_t)r * NN, nsrc + r * 16, wl, bl, xlb,
            hotlist + (size_t)r * NN, nhot + r * 16, wr, br, xrh,
            128, stride, HP);
        edge_all<<<6144, 256, 0, stream>>>(
            solosrc, solodst, nsolo,
            csroff, rsrcx, eacsr, relemb + (size_t)lr * RED,
            linew + ((size_t)lr * 512 + hpBase * 128) * 24,
            attw + (size_t)lr * 512 + hpBase * 128,
            xlb, xrh, hotlist, nhot, hmsg, gate, r, HP, stride, 2048);
      }
    }
    add_ln<<<(NN + 3) / 4, 256, 0, stream>>>(h, hmsg, cb, n1w + l * HID, n1b + l * HID, hbf, NN);
    gemm_bf16<<<8 * RPX * 2, 256, 0, stream>>>(hbf, f1wb + (size_t)l * 256 * 128,
                                               f1bias + (size_t)l * 256, nullptr, f1buf,
                                               NN, 128, 256, 1, 2);
    gemm_bf16<<<8 * RPX, 256, 0, stream>>>(f1buf, f2wb + (size_t)l * 128 * 256,
                                           f2bias + (size_t)l * 128, hmsg, nullptr,
                                           NN, 256, 128, 0, 1);
    add_ln<<<(NN + 3) / 4, 256, 0, stream>>>(h, hmsg, nullptr, n2w + l * HID, n2b + l * HID, hbf, NN);
  }

  group_bounds<<<1, 128, 0, stream>>>(batch, gstart);
  readout_part2<<<dim3(NG, 8), 128, 0, stream>>>(h, gstart, psum, pmax);
  readout_final<<<NG, 256, 0, stream>>>(gstart, psum, pmax, rnw, rnb, g);
  kan1_part<<<dim3(NG, 8), 128, 0, stream>>>(g, bw1, sw1, sc1, grid1, zpart);
  kan2<<<NG, 128, 0, stream>>>(zpart, bw2, sw2, sc2, grid2, out);
}